// Round 2
// baseline (583.903 us; speedup 1.0000x reference)
//
#include <hip/hip_runtime.h>
#include <cmath>
#include <cstdint>

#define NB 8
#define NL 16
#define TD 8192
#define NPIX 65536
#define CH 32
#define SD 512

static constexpr uint32_t PRIME = 2654435761u;

struct LevelParams {
    int res[NL];
    int hashed[NL];
    int coff[NL + 1];
    int total;
};

// ---- bf16 helpers (RNE) ----
__device__ __forceinline__ unsigned short f2bf(float f) {
    uint32_t u = __float_as_uint(f);
    return (unsigned short)((u + 0x7fffu + ((u >> 16) & 1u)) >> 16);
}
__device__ __forceinline__ float bflo(uint32_t u) { return __uint_as_float(u << 16); }
__device__ __forceinline__ float bfhi(uint32_t u) { return __uint_as_float(u & 0xffff0000u); }
__device__ __forceinline__ uint32_t packbf(float a, float b) {
    return (uint32_t)f2bf(a) | ((uint32_t)f2bf(b) << 16);
}

// ---- K0: styles[b][c] and dcoef[b][o] (tiny) ----
__global__ void k_styles(const float* __restrict__ s, const float* __restrict__ aw,
                         const float* __restrict__ ab, const float* __restrict__ cw,
                         float* __restrict__ styles, float* __restrict__ dcoef) {
    int t = threadIdx.x;
    int b = t >> 5, c = t & 31;
    const float* sv = s + b * SD;
    const float* wv = aw + c * SD;
    float acc = 0.f;
    for (int k = 0; k < SD; ++k) acc += sv[k] * wv[k];
    float st = acc * 0.04419417382415922f /* 1/sqrt(512) */ + ab[c];
    styles[b * CH + c] = st;
    __shared__ float st_sh[NB * CH];
    st_sh[b * CH + c] = st;
    __syncthreads();
    float d = 0.f;
    for (int i = 0; i < CH; ++i) {
        const float* w9 = cw + (c * CH + i) * 9;
        float ws = 0.f;
        #pragma unroll
        for (int k = 0; k < 9; ++k) ws += w9[k] * w9[k];
        float si = st_sh[b * CH + i];
        d += ws * si * si;
    }
    dcoef[b * CH + c] = rsqrtf(d + 1e-8f);
}

// ---- K1: hash retrieve + style modulation -> xm (bf16x2 per level-pair) ----
__global__ void k_retrieve(const float* __restrict__ tables,
                           const float* __restrict__ coords,
                           const float* __restrict__ styles,
                           uint32_t* __restrict__ xm,
                           LevelParams p) {
    int n = blockIdx.x * 256 + threadIdx.x;   // pixel
    int b = blockIdx.y;
    float cxv = coords[2 * n];
    float cyv = coords[2 * n + 1];
    const float* tb = tables + (size_t)b * NL * TD * 2;
    for (int l = 0; l < NL; ++l) {
        int r = p.res[l];
        float rm1 = (float)(r - 1);
        float px = cxv * rm1, py = cyv * rm1;
        float fxf = floorf(px), fyf = floorf(py);
        float fx = px - fxf, fy = py - fyf;       // frac from UNclipped floor (ref semantics)
        int x0 = min((int)fxf, r - 2);
        int y0 = min((int)fyf, r - 2);
        uint32_t i00, i10, i01, i11;
        if (p.hashed[l]) {
            uint32_t hy0 = (uint32_t)y0 * PRIME, hy1 = (uint32_t)(y0 + 1) * PRIME;
            i00 = ((uint32_t)x0 ^ hy0) & (TD - 1);
            i10 = ((uint32_t)(x0 + 1) ^ hy0) & (TD - 1);
            i01 = ((uint32_t)x0 ^ hy1) & (TD - 1);
            i11 = ((uint32_t)(x0 + 1) ^ hy1) & (TD - 1);
        } else {
            i00 = (uint32_t)(y0 * r + x0); i10 = i00 + 1;
            i01 = i00 + r;                 i11 = i01 + 1;
        }
        const float* tl = tb + l * TD * 2;
        float2 g00 = *(const float2*)(tl + 2 * i00);
        float2 g10 = *(const float2*)(tl + 2 * i10);
        float2 g01 = *(const float2*)(tl + 2 * i01);
        float2 g11 = *(const float2*)(tl + 2 * i11);
        float w00 = (1.f - fx) * (1.f - fy), w10 = fx * (1.f - fy);
        float w01 = (1.f - fx) * fy,         w11 = fx * fy;
        float f0 = w00 * g00.x + w10 * g10.x + w01 * g01.x + w11 * g11.x;
        float f1 = w00 * g00.y + w10 * g10.y + w01 * g01.y + w11 * g11.y;
        float s0 = styles[b * CH + 2 * l], s1 = styles[b * CH + 2 * l + 1];
        xm[(size_t)(b * NL + l) * NPIX + n] = packbf(f0 * s0, f1 * s1);
    }
}

// ---- K2: modulated 3x3 conv + demod + bias + lrelu*sqrt2 -> tokens ----
// 16x16 pixel tile per block; thread = 4 out-ch x 8 px register block.
__global__ __launch_bounds__(256) void k_conv(
    const uint32_t* __restrict__ xm, const float* __restrict__ cw,
    const float* __restrict__ cb, const float* __restrict__ dcoef,
    uint32_t* __restrict__ tokens) {
    __shared__ uint32_t xt[NL][18][18];        // bf16x2 pairs, 20736 B
    __shared__ float wt[CH][3][3][CH];         // [i][ky][kx][o], 36864 B
    int b = blockIdx.z;
    int ty0 = blockIdx.y * 16, tx0 = blockIdx.x * 16;
    int tid = threadIdx.x;
    for (int idx = tid; idx < CH * CH * 9; idx += 256) {
        int o = idx / (CH * 9); int rem = idx - o * CH * 9;
        int i = rem / 9; int k = rem - i * 9;
        wt[i][k / 3][k % 3][o] = cw[idx];
    }
    for (int idx = tid; idx < NL * 18 * 18; idx += 256) {
        int lp = idx / 324; int rem = idx - lp * 324;
        int rr = rem / 18, cc = rem - rr * 18;
        int gy = ty0 + rr - 1, gx = tx0 + cc - 1;
        uint32_t v = 0;
        if (gy >= 0 && gy < 256 && gx >= 0 && gx < 256)
            v = xm[(size_t)(b * NL + lp) * NPIX + gy * 256 + gx];
        xt[lp][rr][cc] = v;
    }
    __syncthreads();
    int og = tid & 7;          // 8 o-groups of 4
    int strip = tid >> 3;      // 32 strips (16 rows x 2 half-rows)
    int row = strip >> 1;
    int xh = (strip & 1) * 8;
    float acc[4][8] = {};
    for (int lp = 0; lp < NL; ++lp) {
        #pragma unroll
        for (int ky = 0; ky < 3; ++ky) {
            float xr0[10], xr1[10];
            #pragma unroll
            for (int q = 0; q < 10; ++q) {
                uint32_t u = xt[lp][row + ky][xh + q];
                xr0[q] = bflo(u); xr1[q] = bfhi(u);
            }
            #pragma unroll
            for (int kx = 0; kx < 3; ++kx) {
                float4 wa = *(const float4*)&wt[2 * lp][ky][kx][og * 4];
                float4 wb = *(const float4*)&wt[2 * lp + 1][ky][kx][og * 4];
                #pragma unroll
                for (int pq = 0; pq < 8; ++pq) {
                    acc[0][pq] += wa.x * xr0[pq + kx];
                    acc[0][pq] += wb.x * xr1[pq + kx];
                    acc[1][pq] += wa.y * xr0[pq + kx];
                    acc[1][pq] += wb.y * xr1[pq + kx];
                    acc[2][pq] += wa.z * xr0[pq + kx];
                    acc[2][pq] += wb.z * xr1[pq + kx];
                    acc[3][pq] += wa.w * xr0[pq + kx];
                    acc[3][pq] += wb.w * xr1[pq + kx];
                }
            }
        }
    }
    int gy = ty0 + row, gxb = tx0 + xh;
    #pragma unroll
    for (int pp = 0; pp < 2; ++pp) {
        int o0 = og * 4 + pp * 2, o1 = o0 + 1;
        float d0 = dcoef[b * CH + o0], d1 = dcoef[b * CH + o1];
        float bb0 = cb[o0], bb1 = cb[o1];
        int lpair = og * 2 + pp;               // channel pair (2*lpair, 2*lpair+1)
        #pragma unroll
        for (int pq = 0; pq < 8; ++pq) {
            float y0 = acc[pp * 2][pq] * d0 + bb0;
            float y1 = acc[pp * 2 + 1][pq] * d1 + bb1;
            y0 = (y0 > 0.f ? y0 : 0.2f * y0) * 1.4142135623730951f;
            y1 = (y1 > 0.f ? y1 : 0.2f * y1) * 1.4142135623730951f;
            tokens[(size_t)(b * NL + lpair) * NPIX + gy * 256 + gxb + pq] = packbf(y0, y1);
        }
    }
}

// ---- K3: inverted scatter — each table corner gathers its pixel window ----
__global__ void k_recon(const uint32_t* __restrict__ tokens,
                        const float* __restrict__ coords,
                        float* __restrict__ R, LevelParams p) {
    int gid = blockIdx.x * 256 + threadIdx.x;
    int b = blockIdx.y;
    if (gid >= p.total) return;
    int l = 0;
    #pragma unroll
    for (int q = 1; q < NL; ++q) if (gid >= p.coff[q]) l = q;
    int cid = gid - p.coff[l];
    int r = p.res[l];
    int cy = cid / r;
    int cx = cid - cy * r;
    float rm1 = (float)(r - 1);
    float sc = 255.f / rm1;
    int jlo = max(0, (int)floorf((cx - 1) * sc) - 1);
    int jhi = min(255, (int)ceilf((cx + 1) * sc) + 1);
    int ilo = max(0, (int)floorf((cy - 1) * sc) - 1);
    int ihi = min(255, (int)ceilf((cy + 1) * sc) + 1);
    const uint32_t* tl = tokens + (size_t)(b * NL + l) * NPIX;
    float a0 = 0.f, a1 = 0.f;
    for (int i = ilo; i <= ihi; ++i) {
        float py = coords[i * 512 + 1] * rm1;   // y-coord of row i (exact input)
        float fyf = floorf(py);
        float fy = py - fyf;
        int y0 = min((int)fyf, r - 2);
        float wy = (y0 == cy) ? (1.f - fy) : ((y0 + 1 == cy) ? fy : 0.f);
        if (wy == 0.f) continue;
        float s0 = 0.f, s1 = 0.f;
        for (int j = jlo; j <= jhi; ++j) {
            float px = coords[2 * j] * rm1;     // x-coord of col j (exact input)
            float fxf = floorf(px);
            float fx = px - fxf;
            int x0 = min((int)fxf, r - 2);
            float wx = (x0 == cx) ? (1.f - fx) : ((x0 + 1 == cx) ? fx : 0.f);
            if (wx != 0.f) {
                uint32_t t = tl[i * 256 + j];
                s0 += wx * bflo(t);
                s1 += wx * bfhi(t);
            }
        }
        a0 += wy * s0;
        a1 += wy * s1;
    }
    float* Rbl = R + (size_t)(b * NL + l) * TD * 2;
    if (p.hashed[l]) {
        uint32_t h = ((uint32_t)cx ^ ((uint32_t)cy * PRIME)) & (TD - 1);
        atomicAdd(&Rbl[2 * h], a0);
        atomicAdd(&Rbl[2 * h + 1], a1);
    } else {
        int t = cy * r + cx;                    // bijective -> race-free plain store
        Rbl[2 * t] = a0;
        Rbl[2 * t + 1] = a1;
    }
}

// ---- K4: residual + LayerNorm(16384) -> FP32 out ----
__global__ void k_ln(const float* __restrict__ R, const float* __restrict__ inp,
                     float* __restrict__ out) {
    int row = blockIdx.x;                       // b*NL + l
    const float4* rv = (const float4*)(R + (size_t)row * 16384);
    const float4* iv = (const float4*)(inp + (size_t)row * 16384);
    int tid = threadIdx.x;
    float sum = 0.f, ssq = 0.f;
    for (int k = tid; k < 4096; k += 256) {
        float4 a = rv[k], c = iv[k];
        float x0 = a.x + c.x, x1 = a.y + c.y, x2 = a.z + c.z, x3 = a.w + c.w;
        sum += x0 + x1 + x2 + x3;
        ssq += x0 * x0 + x1 * x1 + x2 * x2 + x3 * x3;
    }
    #pragma unroll
    for (int off = 32; off > 0; off >>= 1) {
        sum += __shfl_xor(sum, off, 64);
        ssq += __shfl_xor(ssq, off, 64);
    }
    __shared__ float red[8];
    int w = tid >> 6;
    if ((tid & 63) == 0) { red[w * 2] = sum; red[w * 2 + 1] = ssq; }
    __syncthreads();
    sum = red[0] + red[2] + red[4] + red[6];
    ssq = red[1] + red[3] + red[5] + red[7];
    float mu = sum * (1.f / 16384.f);
    float var = ssq * (1.f / 16384.f) - mu * mu;
    float inv = rsqrtf(var + 1e-5f);
    float4* ob = (float4*)(out + (size_t)row * 16384);
    for (int k = tid; k < 4096; k += 256) {
        float4 a = rv[k], c = iv[k];
        float4 o4;
        o4.x = (a.x + c.x - mu) * inv;
        o4.y = (a.y + c.y - mu) * inv;
        o4.z = (a.z + c.z - mu) * inv;
        o4.w = (a.w + c.w - mu) * inv;
        ob[k] = o4;
    }
}

extern "C" void kernel_launch(void* const* d_in, const int* in_sizes, int n_in,
                              void* d_out, int out_size, void* d_ws, size_t ws_size,
                              hipStream_t stream) {
    const float* inputs = (const float*)d_in[0];
    const float* s      = (const float*)d_in[1];
    const float* coords = (const float*)d_in[2];
    const float* aw     = (const float*)d_in[3];
    const float* ab     = (const float*)d_in[4];
    const float* cw     = (const float*)d_in[5];
    const float* cb     = (const float*)d_in[6];

    char* ws = (char*)d_ws;
    uint32_t* xm     = (uint32_t*)(ws);                 // 33,554,432 B
    uint32_t* tokens = (uint32_t*)(ws + 33554432);      // 33,554,432 B
    float*    R      = (float*)(ws + 67108864);         //  8,388,608 B
    float*    styles = (float*)(ws + 75497472);
    float*    dcoef  = (float*)(ws + 75498496);

    // RES_LIST exactly as numpy computes it (double libm ops).
    LevelParams p;
    double bb = exp((log(256.0) - log(16.0)) / 15.0);
    p.coff[0] = 0;
    for (int l = 0; l < NL; ++l) {
        int r = (int)floor(16.0 * pow(bb, (double)l));
        p.res[l] = r;
        p.hashed[l] = (r * r > TD) ? 1 : 0;
        p.coff[l + 1] = p.coff[l] + r * r;
    }
    p.total = p.coff[NL];

    hipMemsetAsync(R, 0, (size_t)NB * NL * TD * 2 * sizeof(float), stream);
    hipLaunchKernelGGL(k_styles, dim3(1), dim3(256), 0, stream, s, aw, ab, cw, styles, dcoef);
    hipLaunchKernelGGL(k_retrieve, dim3(256, NB), dim3(256), 0, stream,
                       inputs, coords, styles, xm, p);
    hipLaunchKernelGGL(k_conv, dim3(16, 16, NB), dim3(256), 0, stream,
                       xm, cw, cb, dcoef, tokens);
    int rblocks = (p.total + 255) / 256;
    hipLaunchKernelGGL(k_recon, dim3(rblocks, NB), dim3(256), 0, stream,
                       tokens, coords, R, p);
    hipLaunchKernelGGL(k_ln, dim3(NB * NL), dim3(256), 0, stream,
                       R, inputs, (unsigned short*)d_out ? (float*)d_out : (float*)d_out);
}

// Round 3
// 383.745 us; speedup vs baseline: 1.5216x; 1.5216x over previous
//
#include <hip/hip_runtime.h>
#include <cmath>
#include <cstdint>

#define NB 8
#define NL 16
#define TD 8192
#define NPIX 65536
#define CH 32
#define SD 512

static constexpr uint32_t PRIME = 2654435761u;

struct LevelParams {
    int res[NL];
    int hashed[NL];
    int roff[NL];    // prefix sum of res
    int uoff[NL];    // prefix sum of res*512 (floats) into U
    int sumr;
};

// ---- bf16 helpers (RNE) ----
__device__ __forceinline__ unsigned short f2bf(float f) {
    uint32_t u = __float_as_uint(f);
    return (unsigned short)((u + 0x7fffu + ((u >> 16) & 1u)) >> 16);
}
__device__ __forceinline__ float bflo(uint32_t u) { return __uint_as_float(u << 16); }
__device__ __forceinline__ float bfhi(uint32_t u) { return __uint_as_float(u & 0xffff0000u); }
__device__ __forceinline__ uint32_t packbf(float a, float b) {
    return (uint32_t)f2bf(a) | ((uint32_t)f2bf(b) << 16);
}

// ---- K0: styles[b][c] and dcoef[b][o] (tiny) ----
__global__ void k_styles(const float* __restrict__ s, const float* __restrict__ aw,
                         const float* __restrict__ ab, const float* __restrict__ cw,
                         float* __restrict__ styles, float* __restrict__ dcoef) {
    int t = threadIdx.x;
    int b = t >> 5, c = t & 31;
    const float* sv = s + b * SD;
    const float* wv = aw + c * SD;
    float acc = 0.f;
    for (int k = 0; k < SD; ++k) acc += sv[k] * wv[k];
    float st = acc * 0.04419417382415922f /* 1/sqrt(512) */ + ab[c];
    styles[b * CH + c] = st;
    __shared__ float st_sh[NB * CH];
    st_sh[b * CH + c] = st;
    __syncthreads();
    float d = 0.f;
    for (int i = 0; i < CH; ++i) {
        const float* w9 = cw + (c * CH + i) * 9;
        float ws = 0.f;
        #pragma unroll
        for (int k = 0; k < 9; ++k) ws += w9[k] * w9[k];
        float si = st_sh[b * CH + i];
        d += ws * si * si;
    }
    dcoef[b * CH + c] = rsqrtf(d + 1e-8f);
}

// ---- K1: hash retrieve + style modulation -> xm (bf16x2 per level-pair) ----
__global__ void k_retrieve(const float* __restrict__ tables,
                           const float* __restrict__ coords,
                           const float* __restrict__ styles,
                           uint32_t* __restrict__ xm,
                           LevelParams p) {
    int n = blockIdx.x * 256 + threadIdx.x;   // pixel
    int b = blockIdx.y;
    float cxv = coords[2 * n];
    float cyv = coords[2 * n + 1];
    const float* tb = tables + (size_t)b * NL * TD * 2;
    for (int l = 0; l < NL; ++l) {
        int r = p.res[l];
        float rm1 = (float)(r - 1);
        float px = cxv * rm1, py = cyv * rm1;
        float fxf = floorf(px), fyf = floorf(py);
        float fx = px - fxf, fy = py - fyf;       // frac from UNclipped floor (ref semantics)
        int x0 = min((int)fxf, r - 2);
        int y0 = min((int)fyf, r - 2);
        uint32_t i00, i10, i01, i11;
        if (p.hashed[l]) {
            uint32_t hy0 = (uint32_t)y0 * PRIME, hy1 = (uint32_t)(y0 + 1) * PRIME;
            i00 = ((uint32_t)x0 ^ hy0) & (TD - 1);
            i10 = ((uint32_t)(x0 + 1) ^ hy0) & (TD - 1);
            i01 = ((uint32_t)x0 ^ hy1) & (TD - 1);
            i11 = ((uint32_t)(x0 + 1) ^ hy1) & (TD - 1);
        } else {
            i00 = (uint32_t)(y0 * r + x0); i10 = i00 + 1;
            i01 = i00 + r;                 i11 = i01 + 1;
        }
        const float* tl = tb + l * TD * 2;
        float2 g00 = *(const float2*)(tl + 2 * i00);
        float2 g10 = *(const float2*)(tl + 2 * i10);
        float2 g01 = *(const float2*)(tl + 2 * i01);
        float2 g11 = *(const float2*)(tl + 2 * i11);
        float w00 = (1.f - fx) * (1.f - fy), w10 = fx * (1.f - fy);
        float w01 = (1.f - fx) * fy,         w11 = fx * fy;
        float f0 = w00 * g00.x + w10 * g10.x + w01 * g01.x + w11 * g11.x;
        float f1 = w00 * g00.y + w10 * g10.y + w01 * g01.y + w11 * g11.y;
        float s0 = styles[b * CH + 2 * l], s1 = styles[b * CH + 2 * l + 1];
        xm[(size_t)(b * NL + l) * NPIX + n] = packbf(f0 * s0, f1 * s1);
    }
}

// ---- K2: modulated 3x3 conv + demod + bias + lrelu*sqrt2 -> tokens ----
__global__ __launch_bounds__(256) void k_conv(
    const uint32_t* __restrict__ xm, const float* __restrict__ cw,
    const float* __restrict__ cb, const float* __restrict__ dcoef,
    uint32_t* __restrict__ tokens) {
    __shared__ uint32_t xt[NL][18][18];        // bf16x2 pairs, 20736 B
    __shared__ float wt[CH][3][3][CH];         // [i][ky][kx][o], 36864 B
    int b = blockIdx.z;
    int ty0 = blockIdx.y * 16, tx0 = blockIdx.x * 16;
    int tid = threadIdx.x;
    for (int idx = tid; idx < CH * CH * 9; idx += 256) {
        int o = idx / (CH * 9); int rem = idx - o * CH * 9;
        int i = rem / 9; int k = rem - i * 9;
        wt[i][k / 3][k % 3][o] = cw[idx];
    }
    for (int idx = tid; idx < NL * 18 * 18; idx += 256) {
        int lp = idx / 324; int rem = idx - lp * 324;
        int rr = rem / 18, cc = rem - rr * 18;
        int gy = ty0 + rr - 1, gx = tx0 + cc - 1;
        uint32_t v = 0;
        if (gy >= 0 && gy < 256 && gx >= 0 && gx < 256)
            v = xm[(size_t)(b * NL + lp) * NPIX + gy * 256 + gx];
        xt[lp][rr][cc] = v;
    }
    __syncthreads();
    int og = tid & 7;          // 8 o-groups of 4
    int strip = tid >> 3;      // 32 strips (16 rows x 2 half-rows)
    int row = strip >> 1;
    int xh = (strip & 1) * 8;
    float acc[4][8] = {};
    for (int lp = 0; lp < NL; ++lp) {
        #pragma unroll
        for (int ky = 0; ky < 3; ++ky) {
            float xr0[10], xr1[10];
            #pragma unroll
            for (int q = 0; q < 10; ++q) {
                uint32_t u = xt[lp][row + ky][xh + q];
                xr0[q] = bflo(u); xr1[q] = bfhi(u);
            }
            #pragma unroll
            for (int kx = 0; kx < 3; ++kx) {
                float4 wa = *(const float4*)&wt[2 * lp][ky][kx][og * 4];
                float4 wb = *(const float4*)&wt[2 * lp + 1][ky][kx][og * 4];
                #pragma unroll
                for (int pq = 0; pq < 8; ++pq) {
                    acc[0][pq] += wa.x * xr0[pq + kx];
                    acc[0][pq] += wb.x * xr1[pq + kx];
                    acc[1][pq] += wa.y * xr0[pq + kx];
                    acc[1][pq] += wb.y * xr1[pq + kx];
                    acc[2][pq] += wa.z * xr0[pq + kx];
                    acc[2][pq] += wb.z * xr1[pq + kx];
                    acc[3][pq] += wa.w * xr0[pq + kx];
                    acc[3][pq] += wb.w * xr1[pq + kx];
                }
            }
        }
    }
    int gy = ty0 + row, gxb = tx0 + xh;
    #pragma unroll
    for (int pp = 0; pp < 2; ++pp) {
        int o0 = og * 4 + pp * 2, o1 = o0 + 1;
        float d0 = dcoef[b * CH + o0], d1 = dcoef[b * CH + o1];
        float bb0 = cb[o0], bb1 = cb[o1];
        int lpair = og * 2 + pp;               // channel pair (2*lpair, 2*lpair+1)
        #pragma unroll
        for (int pq = 0; pq < 8; ++pq) {
            float y0 = acc[pp * 2][pq] * d0 + bb0;
            float y1 = acc[pp * 2 + 1][pq] * d1 + bb1;
            y0 = (y0 > 0.f ? y0 : 0.2f * y0) * 1.4142135623730951f;
            y1 = (y1 > 0.f ? y1 : 0.2f * y1) * 1.4142135623730951f;
            tokens[(size_t)(b * NL + lpair) * NPIX + gy * 256 + gxb + pq] = packbf(y0, y1);
        }
    }
}

// ---- K_wtab: per-level per-grid-position (cell, frac) tables ----
__global__ void k_wtab(const float* __restrict__ coords, int* __restrict__ ctab,
                       float* __restrict__ ftab, LevelParams p) {
    int j = threadIdx.x;                       // 256
    float g = coords[2 * j];                   // x-coord of column j == y-coord of row j
    for (int l = 0; l < NL; ++l) {
        int r = p.res[l];
        float px = g * (float)(r - 1);
        float fl = floorf(px);
        float f = px - fl;                     // frac from UNclipped floor
        int c = min((int)fl, r - 2);
        ctab[l * 256 + j] = c;
        ftab[l * 256 + j] = f;
    }
}

// ---- K3a: separable recon stage 1 — reduce over pixel columns j ----
// thread = (b, l, row i); streams token row; running cell accumulation;
// wave-uniform flushes -> coalesced float2 stores, no atomics.
// U layout: [b][l][cx][i][2] floats, per-level offset p.uoff[l].
__global__ __launch_bounds__(128) void k_recon1(const uint32_t* __restrict__ tokens,
                                                const int* __restrict__ ctab,
                                                const float* __restrict__ ftab,
                                                float* __restrict__ U, LevelParams p) {
    int l = blockIdx.x, half = blockIdx.y, b = blockIdx.z;
    int i = half * 128 + threadIdx.x;
    __shared__ int cs[256];
    __shared__ float fs[256];
    for (int t = threadIdx.x; t < 256; t += 128) {
        cs[t] = ctab[l * 256 + t];
        fs[t] = ftab[l * 256 + t];
    }
    __syncthreads();
    const uint32_t* trow = tokens + (size_t)(b * NL + l) * NPIX + i * 256;
    float* Ub = U + (size_t)b * (p.sumr * 512) + p.uoff[l] + i * 2;
    int curc = 0;
    float aL0 = 0.f, aL1 = 0.f, aR0 = 0.f, aR1 = 0.f;
    #pragma unroll 4
    for (int j = 0; j < 256; j += 4) {
        uint4 tv = *(const uint4*)(trow + j);
        #pragma unroll
        for (int q = 0; q < 4; ++q) {
            uint32_t u = (&tv.x)[q];
            int c = cs[j + q];
            float f = fs[j + q];
            while (c != curc) {                // uniform across wave
                *(float2*)(Ub + (size_t)curc * 512) = make_float2(aL0, aL1);
                aL0 = aR0; aL1 = aR1; aR0 = 0.f; aR1 = 0.f;
                ++curc;
            }
            float t0 = bflo(u), t1 = bfhi(u);
            float wA = 1.f - f;
            aL0 += wA * t0; aL1 += wA * t1;
            aR0 += f * t0;  aR1 += f * t1;
        }
    }
    *(float2*)(Ub + (size_t)curc * 512) = make_float2(aL0, aL1);
    *(float2*)(Ub + (size_t)(curc + 1) * 512) = make_float2(aR0, aR1);
}

// ---- K3b: separable recon stage 2 — reduce over rows i, emit corners ----
// thread = (b, l, cx); per-thread contiguous float2 stream over i.
__global__ void k_recon2(const float* __restrict__ U, const int* __restrict__ ctab,
                         const float* __restrict__ ftab, float* __restrict__ R,
                         LevelParams p) {
    int wid = blockIdx.x * 256 + threadIdx.x;
    int b = blockIdx.y;
    if (wid >= p.sumr) return;
    int l = 0;
    #pragma unroll
    for (int q = 1; q < NL; ++q) if (wid >= p.roff[q]) l = q;
    int cx = wid - p.roff[l];
    int r = p.res[l];
    int hashed = p.hashed[l];
    const float* Ub = U + (size_t)b * (p.sumr * 512) + p.uoff[l] + (size_t)cx * 512;
    float* Rbl = R + (size_t)(b * NL + l) * TD * 2;
    const int* crow = ctab + l * 256;
    const float* frow = ftab + l * 256;
    int curc = 0;
    float aL0 = 0.f, aL1 = 0.f, aR0 = 0.f, aR1 = 0.f;
    #pragma unroll 8
    for (int i = 0; i < 256; ++i) {
        int c = crow[i];
        float f = frow[i];
        while (c != curc) {
            if (hashed) {
                uint32_t h = ((uint32_t)cx ^ ((uint32_t)curc * PRIME)) & (TD - 1);
                atomicAdd(&Rbl[2 * h], aL0);
                atomicAdd(&Rbl[2 * h + 1], aL1);
            } else {
                *(float2*)(Rbl + 2 * (curc * r + cx)) = make_float2(aL0, aL1);
            }
            aL0 = aR0; aL1 = aR1; aR0 = 0.f; aR1 = 0.f;
            ++curc;
        }
        float2 u = *(const float2*)(Ub + i * 2);
        float wA = 1.f - f;
        aL0 += wA * u.x; aL1 += wA * u.y;
        aR0 += f * u.x;  aR1 += f * u.y;
    }
    if (hashed) {
        uint32_t h0 = ((uint32_t)cx ^ ((uint32_t)curc * PRIME)) & (TD - 1);
        atomicAdd(&Rbl[2 * h0], aL0);
        atomicAdd(&Rbl[2 * h0 + 1], aL1);
        uint32_t h1 = ((uint32_t)cx ^ ((uint32_t)(curc + 1) * PRIME)) & (TD - 1);
        atomicAdd(&Rbl[2 * h1], aR0);
        atomicAdd(&Rbl[2 * h1 + 1], aR1);
    } else {
        *(float2*)(Rbl + 2 * (curc * r + cx)) = make_float2(aL0, aL1);
        *(float2*)(Rbl + 2 * ((curc + 1) * r + cx)) = make_float2(aR0, aR1);
    }
}

// ---- K4: residual + LayerNorm(16384) -> FP32 out ----
__global__ void k_ln(const float* __restrict__ R, const float* __restrict__ inp,
                     float* __restrict__ out) {
    int row = blockIdx.x;                       // b*NL + l
    const float4* rv = (const float4*)(R + (size_t)row * 16384);
    const float4* iv = (const float4*)(inp + (size_t)row * 16384);
    int tid = threadIdx.x;
    float sum = 0.f, ssq = 0.f;
    for (int k = tid; k < 4096; k += 256) {
        float4 a = rv[k], c = iv[k];
        float x0 = a.x + c.x, x1 = a.y + c.y, x2 = a.z + c.z, x3 = a.w + c.w;
        sum += x0 + x1 + x2 + x3;
        ssq += x0 * x0 + x1 * x1 + x2 * x2 + x3 * x3;
    }
    #pragma unroll
    for (int off = 32; off > 0; off >>= 1) {
        sum += __shfl_xor(sum, off, 64);
        ssq += __shfl_xor(ssq, off, 64);
    }
    __shared__ float red[8];
    int w = tid >> 6;
    if ((tid & 63) == 0) { red[w * 2] = sum; red[w * 2 + 1] = ssq; }
    __syncthreads();
    sum = red[0] + red[2] + red[4] + red[6];
    ssq = red[1] + red[3] + red[5] + red[7];
    float mu = sum * (1.f / 16384.f);
    float var = ssq * (1.f / 16384.f) - mu * mu;
    float inv = rsqrtf(var + 1e-5f);
    float4* ob = (float4*)(out + (size_t)row * 16384);
    for (int k = tid; k < 4096; k += 256) {
        float4 a = rv[k], c = iv[k];
        float4 o4;
        o4.x = (a.x + c.x - mu) * inv;
        o4.y = (a.y + c.y - mu) * inv;
        o4.z = (a.z + c.z - mu) * inv;
        o4.w = (a.w + c.w - mu) * inv;
        ob[k] = o4;
    }
}

extern "C" void kernel_launch(void* const* d_in, const int* in_sizes, int n_in,
                              void* d_out, int out_size, void* d_ws, size_t ws_size,
                              hipStream_t stream) {
    const float* inputs = (const float*)d_in[0];
    const float* s      = (const float*)d_in[1];
    const float* coords = (const float*)d_in[2];
    const float* aw     = (const float*)d_in[3];
    const float* ab     = (const float*)d_in[4];
    const float* cw     = (const float*)d_in[5];
    const float* cb     = (const float*)d_in[6];

    char* ws = (char*)d_ws;
    uint32_t* xm     = (uint32_t*)(ws);                 // 33,554,432 B (reused as U after conv)
    uint32_t* tokens = (uint32_t*)(ws + 33554432);      // 33,554,432 B
    float*    R      = (float*)(ws + 67108864);         //  8,388,608 B
    float*    styles = (float*)(ws + 75497472);         //  1 KB
    float*    dcoef  = (float*)(ws + 75498496);         //  1 KB
    int*      ctab   = (int*)(ws + 75499520);           // 16 KB
    float*    ftab   = (float*)(ws + 75515904);         // 16 KB

    // RES_LIST exactly as numpy computes it (double libm ops).
    LevelParams p;
    double bb = exp((log(256.0) - log(16.0)) / 15.0);
    int roff = 0, uoff = 0;
    for (int l = 0; l < NL; ++l) {
        int r = (int)floor(16.0 * pow(bb, (double)l));
        p.res[l] = r;
        p.hashed[l] = (r * r > TD) ? 1 : 0;
        p.roff[l] = roff;
        p.uoff[l] = uoff;
        roff += r;
        uoff += r * 512;
    }
    p.sumr = roff;

    hipMemsetAsync(R, 0, (size_t)NB * NL * TD * 2 * sizeof(float), stream);
    hipLaunchKernelGGL(k_styles, dim3(1), dim3(256), 0, stream, s, aw, ab, cw, styles, dcoef);
    hipLaunchKernelGGL(k_wtab, dim3(1), dim3(256), 0, stream, coords, ctab, ftab, p);
    hipLaunchKernelGGL(k_retrieve, dim3(256, NB), dim3(256), 0, stream,
                       inputs, coords, styles, xm, p);
    hipLaunchKernelGGL(k_conv, dim3(16, 16, NB), dim3(256), 0, stream,
                       xm, cw, cb, dcoef, tokens);
    float* U = (float*)xm;                              // xm dead after k_conv
    hipLaunchKernelGGL(k_recon1, dim3(NL, 2, NB), dim3(128), 0, stream,
                       tokens, ctab, ftab, U, p);
    int r2blocks = (p.sumr + 255) / 256;
    hipLaunchKernelGGL(k_recon2, dim3(r2blocks, NB), dim3(256), 0, stream,
                       U, ctab, ftab, R, p);
    hipLaunchKernelGGL(k_ln, dim3(NB * NL), dim3(256), 0, stream,
                       R, inputs, (float*)d_out);
}

// Round 4
// 315.732 us; speedup vs baseline: 1.8494x; 1.2154x over previous
//
#include <hip/hip_runtime.h>
#include <cmath>
#include <cstdint>

#define NB 8
#define NL 16
#define TD 8192
#define NPIX 65536
#define CH 32
#define SD 512

static constexpr uint32_t PRIME = 2654435761u;

typedef __attribute__((ext_vector_type(8))) short bf16x8;
typedef __attribute__((ext_vector_type(4))) float f32x4;

struct LevelParams {
    int res[NL];
    int hashed[NL];
    int roff[NL];    // prefix sum of res
    int uoff[NL];    // prefix sum of res*512 (floats) into U
    int sumr;
};

// ---- bf16 helpers (RNE) ----
__device__ __forceinline__ unsigned short f2bf(float f) {
    uint32_t u = __float_as_uint(f);
    return (unsigned short)((u + 0x7fffu + ((u >> 16) & 1u)) >> 16);
}
__device__ __forceinline__ float bflo(uint32_t u) { return __uint_as_float(u << 16); }
__device__ __forceinline__ float bfhi(uint32_t u) { return __uint_as_float(u & 0xffff0000u); }
__device__ __forceinline__ uint32_t packbf(float a, float b) {
    return (uint32_t)f2bf(a) | ((uint32_t)f2bf(b) << 16);
}

// ---- K0: styles[b][c] and dcoef[b][o] (tiny) ----
__global__ void k_styles(const float* __restrict__ s, const float* __restrict__ aw,
                         const float* __restrict__ ab, const float* __restrict__ cw,
                         float* __restrict__ styles, float* __restrict__ dcoef) {
    int t = threadIdx.x;
    int b = t >> 5, c = t & 31;
    const float* sv = s + b * SD;
    const float* wv = aw + c * SD;
    float acc = 0.f;
    for (int k = 0; k < SD; ++k) acc += sv[k] * wv[k];
    float st = acc * 0.04419417382415922f /* 1/sqrt(512) */ + ab[c];
    styles[b * CH + c] = st;
    __shared__ float st_sh[NB * CH];
    st_sh[b * CH + c] = st;
    __syncthreads();
    float d = 0.f;
    for (int i = 0; i < CH; ++i) {
        const float* w9 = cw + (c * CH + i) * 9;
        float ws = 0.f;
        #pragma unroll
        for (int k = 0; k < 9; ++k) ws += w9[k] * w9[k];
        float si = st_sh[b * CH + i];
        d += ws * si * si;
    }
    dcoef[b * CH + c] = rsqrtf(d + 1e-8f);
}

// ---- K_wtab: per-level per-grid-position (cell, frac) tables ----
__global__ void k_wtab(const float* __restrict__ coords, int* __restrict__ ctab,
                       float* __restrict__ ftab, LevelParams p) {
    int j = threadIdx.x;                       // 256
    float g = coords[2 * j];                   // x-coord of column j == y-coord of row j
    for (int l = 0; l < NL; ++l) {
        int r = p.res[l];
        float px = g * (float)(r - 1);
        float fl = floorf(px);
        float f = px - fl;                     // frac from UNclipped floor
        int c = min((int)fl, r - 2);
        ctab[l * 256 + j] = c;
        ftab[l * 256 + j] = f;
    }
}

// ---- K1: hash retrieve + modulation -> xm2 (pixel-contiguous, 16 u32/px) ----
template<int L>
__device__ __forceinline__ uint32_t lvl_fetch(const float* __restrict__ tb,
                                              const float* __restrict__ st,
                                              float cxv, float cyv,
                                              const LevelParams& p) {
    int r = p.res[L];                          // static index into kernarg
    float rm1 = (float)(r - 1);
    float px = cxv * rm1, py = cyv * rm1;
    float fxf = floorf(px), fyf = floorf(py);
    float fx = px - fxf, fy = py - fyf;
    int x0 = min((int)fxf, r - 2);
    int y0 = min((int)fyf, r - 2);
    uint32_t i00, i10, i01, i11;
    if (p.hashed[L]) {
        uint32_t hy0 = (uint32_t)y0 * PRIME, hy1 = (uint32_t)(y0 + 1) * PRIME;
        i00 = ((uint32_t)x0 ^ hy0) & (TD - 1);
        i10 = ((uint32_t)(x0 + 1) ^ hy0) & (TD - 1);
        i01 = ((uint32_t)x0 ^ hy1) & (TD - 1);
        i11 = ((uint32_t)(x0 + 1) ^ hy1) & (TD - 1);
    } else {
        i00 = (uint32_t)(y0 * r + x0); i10 = i00 + 1;
        i01 = i00 + r;                 i11 = i01 + 1;
    }
    const float* tl = tb + L * TD * 2;
    float2 g00 = *(const float2*)(tl + 2 * i00);
    float2 g10 = *(const float2*)(tl + 2 * i10);
    float2 g01 = *(const float2*)(tl + 2 * i01);
    float2 g11 = *(const float2*)(tl + 2 * i11);
    float w00 = (1.f - fx) * (1.f - fy), w10 = fx * (1.f - fy);
    float w01 = (1.f - fx) * fy,         w11 = fx * fy;
    float f0 = w00 * g00.x + w10 * g10.x + w01 * g01.x + w11 * g11.x;
    float f1 = w00 * g00.y + w10 * g10.y + w01 * g01.y + w11 * g11.y;
    return packbf(f0 * st[2 * L], f1 * st[2 * L + 1]);
}

template<int L0>
__device__ __forceinline__ uint4 fetch4(const float* __restrict__ tb,
                                        const float* __restrict__ st,
                                        float cxv, float cyv, const LevelParams& p) {
    uint4 v;
    v.x = lvl_fetch<L0 + 0>(tb, st, cxv, cyv, p);
    v.y = lvl_fetch<L0 + 1>(tb, st, cxv, cyv, p);
    v.z = lvl_fetch<L0 + 2>(tb, st, cxv, cyv, p);
    v.w = lvl_fetch<L0 + 3>(tb, st, cxv, cyv, p);
    return v;
}

__global__ void k_retrieve(const float* __restrict__ tables,
                           const float* __restrict__ coords,
                           const float* __restrict__ styles,
                           uint32_t* __restrict__ xm2, LevelParams p) {
    int wg = blockIdx.x;                       // 8192
    int b = wg & 7;                            // batch -> XCD pinning (L2 locality)
    int idx = (wg >> 3) * 256 + threadIdx.x;   // 0..262143
    int n = idx >> 2, q = idx & 3;
    float cxv = coords[2 * n];
    float cyv = coords[2 * n + 1];
    const float* tb = tables + (size_t)b * NL * TD * 2;
    const float* st = styles + b * CH;
    uint4 v;
    switch (q) {
        case 0: v = fetch4<0>(tb, st, cxv, cyv, p); break;
        case 1: v = fetch4<4>(tb, st, cxv, cyv, p); break;
        case 2: v = fetch4<8>(tb, st, cxv, cyv, p); break;
        default: v = fetch4<12>(tb, st, cxv, cyv, p); break;
    }
    *(uint4*)(xm2 + (size_t)b * NPIX * 16 + (size_t)idx * 4) = v;
}

// ---- K2: MFMA modulated 3x3 conv + demod + bias + lrelu*sqrt2 -> tokens ----
// 16x32 px tile + halo (18x34) staged in LDS as 16B chunks, slot = g ^ (col&3).
__global__ __launch_bounds__(256) void k_conv(
    const uint32_t* __restrict__ xm2, const float* __restrict__ cw,
    const float* __restrict__ cb, const float* __restrict__ dcoef,
    uint32_t* __restrict__ tokens) {
    __shared__ uint32_t xt[18 * 34 * 4 * 4];   // 39,168 B
    int b = blockIdx.z;
    int ty0 = blockIdx.y * 16, tx0 = blockIdx.x * 32;
    int tid = threadIdx.x;
    int lane = tid & 63, wv = tid >> 6;
    int npx = lane & 15, kg = lane >> 4;

    // A fragments: w[o=npx'][i=kg*8+j][tap]; o = ob*16 + (lane&15)
    bf16x8 wf[9][2];
    {
        union { bf16x8 v; unsigned short e[8]; } u;
        #pragma unroll
        for (int t = 0; t < 9; ++t) {
            #pragma unroll
            for (int ob = 0; ob < 2; ++ob) {
                int o = ob * 16 + npx;
                #pragma unroll
                for (int j = 0; j < 8; ++j)
                    u.e[j] = f2bf(cw[(o * 32 + kg * 8 + j) * 9 + t]);
                wf[t][ob] = u.v;
            }
        }
    }
    // demod/bias for this lane's out-channels
    float dc[2][4], bs[2][4];
    #pragma unroll
    for (int ob = 0; ob < 2; ++ob)
        #pragma unroll
        for (int rg = 0; rg < 4; ++rg) {
            int oc = ob * 16 + kg * 4 + rg;
            dc[ob][rg] = dcoef[b * CH + oc];
            bs[ob][rg] = cb[oc];
        }

    // stage tile+halo
    for (int idx = tid; idx < 18 * 34 * 4; idx += 256) {
        int pl = idx >> 2, slot = idx & 3;
        int r = pl / 34, c = pl - r * 34;
        int gy = ty0 + r - 1, gx = tx0 + c - 1;
        int g = slot ^ (c & 3);
        uint4 v = make_uint4(0u, 0u, 0u, 0u);
        if ((unsigned)gy < 256u && (unsigned)gx < 256u)
            v = *(const uint4*)(xm2 + ((size_t)(b * NPIX) + gy * 256 + gx) * 16 + g * 4);
        *(uint4*)(xt + (size_t)idx * 4) = v;
    }
    __syncthreads();

    #pragma unroll 1
    for (int it = 0; it < 8; ++it) {
        int grp = it * 4 + wv;                 // 32 groups of 16 px
        int py_l = grp >> 1;
        int px_l = ((grp & 1) << 4) + npx;
        f32x4 a0 = {0.f, 0.f, 0.f, 0.f};
        f32x4 a1 = {0.f, 0.f, 0.f, 0.f};
        #pragma unroll
        for (int ky = 0; ky < 3; ++ky) {
            int rowb = (py_l + ky) * 34;
            #pragma unroll
            for (int kx = 0; kx < 3; ++kx) {
                int cc = px_l + kx;
                bf16x8 bf = *(const bf16x8*)(xt + (((rowb + cc) << 2) + (kg ^ (cc & 3))) * 4);
                a0 = __builtin_amdgcn_mfma_f32_16x16x32_bf16(wf[ky * 3 + kx][0], bf, a0, 0, 0, 0);
                a1 = __builtin_amdgcn_mfma_f32_16x16x32_bf16(wf[ky * 3 + kx][1], bf, a1, 0, 0, 0);
            }
        }
        // epilogue: C row = kg*4+reg (out-ch), col = npx (pixel)
        int py = ty0 + py_l, px = tx0 + px_l;
        size_t pbase = (size_t)py * 256 + px;
        {
            float y0 = a0[0] * dc[0][0] + bs[0][0];
            float y1 = a0[1] * dc[0][1] + bs[0][1];
            float y2 = a0[2] * dc[0][2] + bs[0][2];
            float y3 = a0[3] * dc[0][3] + bs[0][3];
            y0 = (y0 > 0.f ? y0 : 0.2f * y0) * 1.4142135623730951f;
            y1 = (y1 > 0.f ? y1 : 0.2f * y1) * 1.4142135623730951f;
            y2 = (y2 > 0.f ? y2 : 0.2f * y2) * 1.4142135623730951f;
            y3 = (y3 > 0.f ? y3 : 0.2f * y3) * 1.4142135623730951f;
            int lp0 = kg * 2;                  // ob=0
            tokens[((size_t)(b * NL + lp0)) * NPIX + pbase] = packbf(y0, y1);
            tokens[((size_t)(b * NL + lp0 + 1)) * NPIX + pbase] = packbf(y2, y3);
        }
        {
            float y0 = a1[0] * dc[1][0] + bs[1][0];
            float y1 = a1[1] * dc[1][1] + bs[1][1];
            float y2 = a1[2] * dc[1][2] + bs[1][2];
            float y3 = a1[3] * dc[1][3] + bs[1][3];
            y0 = (y0 > 0.f ? y0 : 0.2f * y0) * 1.4142135623730951f;
            y1 = (y1 > 0.f ? y1 : 0.2f * y1) * 1.4142135623730951f;
            y2 = (y2 > 0.f ? y2 : 0.2f * y2) * 1.4142135623730951f;
            y3 = (y3 > 0.f ? y3 : 0.2f * y3) * 1.4142135623730951f;
            int lp0 = 8 + kg * 2;              // ob=1
            tokens[((size_t)(b * NL + lp0)) * NPIX + pbase] = packbf(y0, y1);
            tokens[((size_t)(b * NL + lp0 + 1)) * NPIX + pbase] = packbf(y2, y3);
        }
    }
}

// ---- K3a: separable recon stage 1 — reduce over pixel columns j ----
__global__ __launch_bounds__(128) void k_recon1(const uint32_t* __restrict__ tokens,
                                                const int* __restrict__ ctab,
                                                const float* __restrict__ ftab,
                                                float* __restrict__ U, LevelParams p) {
    int l = blockIdx.x, half = blockIdx.y, b = blockIdx.z;
    int i = half * 128 + threadIdx.x;
    __shared__ int cs[256];
    __shared__ float fs[256];
    for (int t = threadIdx.x; t < 256; t += 128) {
        cs[t] = ctab[l * 256 + t];
        fs[t] = ftab[l * 256 + t];
    }
    __syncthreads();
    const uint32_t* trow = tokens + (size_t)(b * NL + l) * NPIX + i * 256;
    float* Ub = U + (size_t)b * (p.sumr * 512) + p.uoff[l] + i * 2;
    int curc = 0;
    float aL0 = 0.f, aL1 = 0.f, aR0 = 0.f, aR1 = 0.f;
    #pragma unroll 4
    for (int j = 0; j < 256; j += 4) {
        uint4 tv = *(const uint4*)(trow + j);
        #pragma unroll
        for (int q = 0; q < 4; ++q) {
            uint32_t u = (&tv.x)[q];
            int c = cs[j + q];
            float f = fs[j + q];
            while (c != curc) {                // uniform across wave
                *(float2*)(Ub + (size_t)curc * 512) = make_float2(aL0, aL1);
                aL0 = aR0; aL1 = aR1; aR0 = 0.f; aR1 = 0.f;
                ++curc;
            }
            float t0 = bflo(u), t1 = bfhi(u);
            float wA = 1.f - f;
            aL0 += wA * t0; aL1 += wA * t1;
            aR0 += f * t0;  aR1 += f * t1;
        }
    }
    *(float2*)(Ub + (size_t)curc * 512) = make_float2(aL0, aL1);
    *(float2*)(Ub + (size_t)(curc + 1) * 512) = make_float2(aR0, aR1);
}

// ---- K3b: separable recon stage 2 — reduce over rows i, emit corners ----
__global__ void k_recon2(const float* __restrict__ U, const int* __restrict__ ctab,
                         const float* __restrict__ ftab, float* __restrict__ R,
                         LevelParams p) {
    int wid = blockIdx.x * 256 + threadIdx.x;
    int b = blockIdx.y;
    if (wid >= p.sumr) return;
    int l = 0;
    #pragma unroll
    for (int q = 1; q < NL; ++q) if (wid >= p.roff[q]) l = q;
    int cx = wid - p.roff[l];
    int r = p.res[l];
    int hashed = p.hashed[l];
    const float* Ub = U + (size_t)b * (p.sumr * 512) + p.uoff[l] + (size_t)cx * 512;
    float* Rbl = R + (size_t)(b * NL + l) * TD * 2;
    const int* crow = ctab + l * 256;
    const float* frow = ftab + l * 256;
    int curc = 0;
    float aL0 = 0.f, aL1 = 0.f, aR0 = 0.f, aR1 = 0.f;
    #pragma unroll 8
    for (int i = 0; i < 256; ++i) {
        int c = crow[i];
        float f = frow[i];
        while (c != curc) {
            if (hashed) {
                uint32_t h = ((uint32_t)cx ^ ((uint32_t)curc * PRIME)) & (TD - 1);
                atomicAdd(&Rbl[2 * h], aL0);
                atomicAdd(&Rbl[2 * h + 1], aL1);
            } else {
                *(float2*)(Rbl + 2 * (curc * r + cx)) = make_float2(aL0, aL1);
            }
            aL0 = aR0; aL1 = aR1; aR0 = 0.f; aR1 = 0.f;
            ++curc;
        }
        float2 u = *(const float2*)(Ub + i * 2);
        float wA = 1.f - f;
        aL0 += wA * u.x; aL1 += wA * u.y;
        aR0 += f * u.x;  aR1 += f * u.y;
    }
    if (hashed) {
        uint32_t h0 = ((uint32_t)cx ^ ((uint32_t)curc * PRIME)) & (TD - 1);
        atomicAdd(&Rbl[2 * h0], aL0);
        atomicAdd(&Rbl[2 * h0 + 1], aL1);
        uint32_t h1 = ((uint32_t)cx ^ ((uint32_t)(curc + 1) * PRIME)) & (TD - 1);
        atomicAdd(&Rbl[2 * h1], aR0);
        atomicAdd(&Rbl[2 * h1 + 1], aR1);
    } else {
        *(float2*)(Rbl + 2 * (curc * r + cx)) = make_float2(aL0, aL1);
        *(float2*)(Rbl + 2 * ((curc + 1) * r + cx)) = make_float2(aR0, aR1);
    }
}

// ---- K4: residual + LayerNorm(16384) -> FP32 out ----
__global__ void k_ln(const float* __restrict__ R, const float* __restrict__ inp,
                     float* __restrict__ out) {
    int row = blockIdx.x;                       // b*NL + l
    const float4* rv = (const float4*)(R + (size_t)row * 16384);
    const float4* iv = (const float4*)(inp + (size_t)row * 16384);
    int tid = threadIdx.x;
    float sum = 0.f, ssq = 0.f;
    for (int k = tid; k < 4096; k += 256) {
        float4 a = rv[k], c = iv[k];
        float x0 = a.x + c.x, x1 = a.y + c.y, x2 = a.z + c.z, x3 = a.w + c.w;
        sum += x0 + x1 + x2 + x3;
        ssq += x0 * x0 + x1 * x1 + x2 * x2 + x3 * x3;
    }
    #pragma unroll
    for (int off = 32; off > 0; off >>= 1) {
        sum += __shfl_xor(sum, off, 64);
        ssq += __shfl_xor(ssq, off, 64);
    }
    __shared__ float red[8];
    int w = tid >> 6;
    if ((tid & 63) == 0) { red[w * 2] = sum; red[w * 2 + 1] = ssq; }
    __syncthreads();
    sum = red[0] + red[2] + red[4] + red[6];
    ssq = red[1] + red[3] + red[5] + red[7];
    float mu = sum * (1.f / 16384.f);
    float var = ssq * (1.f / 16384.f) - mu * mu;
    float inv = rsqrtf(var + 1e-5f);
    float4* ob = (float4*)(out + (size_t)row * 16384);
    for (int k = tid; k < 4096; k += 256) {
        float4 a = rv[k], c = iv[k];
        float4 o4;
        o4.x = (a.x + c.x - mu) * inv;
        o4.y = (a.y + c.y - mu) * inv;
        o4.z = (a.z + c.z - mu) * inv;
        o4.w = (a.w + c.w - mu) * inv;
        ob[k] = o4;
    }
}

extern "C" void kernel_launch(void* const* d_in, const int* in_sizes, int n_in,
                              void* d_out, int out_size, void* d_ws, size_t ws_size,
                              hipStream_t stream) {
    const float* inputs = (const float*)d_in[0];
    const float* s      = (const float*)d_in[1];
    const float* coords = (const float*)d_in[2];
    const float* aw     = (const float*)d_in[3];
    const float* ab     = (const float*)d_in[4];
    const float* cw     = (const float*)d_in[5];
    const float* cb     = (const float*)d_in[6];

    char* ws = (char*)d_ws;
    uint32_t* xm2    = (uint32_t*)(ws);                 // 33,554,432 B (reused as U after conv)
    uint32_t* tokens = (uint32_t*)(ws + 33554432);      // 33,554,432 B
    float*    R      = (float*)(ws + 67108864);         //  8,388,608 B
    float*    styles = (float*)(ws + 75497472);         //  1 KB
    float*    dcoef  = (float*)(ws + 75498496);         //  1 KB
    int*      ctab   = (int*)(ws + 75499520);           // 16 KB
    float*    ftab   = (float*)(ws + 75515904);         // 16 KB

    // RES_LIST exactly as numpy computes it (double libm ops).
    LevelParams p;
    double bb = exp((log(256.0) - log(16.0)) / 15.0);
    int roff = 0, uoff = 0;
    for (int l = 0; l < NL; ++l) {
        int r = (int)floor(16.0 * pow(bb, (double)l));
        p.res[l] = r;
        p.hashed[l] = (r * r > TD) ? 1 : 0;
        p.roff[l] = roff;
        p.uoff[l] = uoff;
        roff += r;
        uoff += r * 512;
    }
    p.sumr = roff;

    hipMemsetAsync(R, 0, (size_t)NB * NL * TD * 2 * sizeof(float), stream);
    hipLaunchKernelGGL(k_styles, dim3(1), dim3(256), 0, stream, s, aw, ab, cw, styles, dcoef);
    hipLaunchKernelGGL(k_wtab, dim3(1), dim3(256), 0, stream, coords, ctab, ftab, p);
    hipLaunchKernelGGL(k_retrieve, dim3(8192), dim3(256), 0, stream,
                       inputs, coords, styles, xm2, p);
    hipLaunchKernelGGL(k_conv, dim3(8, 16, NB), dim3(256), 0, stream,
                       xm2, cw, cb, dcoef, tokens);
    float* U = (float*)xm2;                             // xm2 dead after k_conv
    hipLaunchKernelGGL(k_recon1, dim3(NL, 2, NB), dim3(128), 0, stream,
                       tokens, ctab, ftab, U, p);
    int r2blocks = (p.sumr + 255) / 256;
    hipLaunchKernelGGL(k_recon2, dim3(r2blocks, NB), dim3(256), 0, stream,
                       U, ctab, ftab, R, p);
    hipLaunchKernelGGL(k_ln, dim3(NB * NL), dim3(256), 0, stream,
                       R, inputs, (float*)d_out);
}

// Round 5
// 260.447 us; speedup vs baseline: 2.2419x; 1.2123x over previous
//
#include <hip/hip_runtime.h>
#include <cmath>
#include <cstdint>

#define NB 8
#define NL 16
#define TD 8192
#define NPIX 65536
#define CH 32
#define SD 512

static constexpr uint32_t PRIME = 2654435761u;

typedef __attribute__((ext_vector_type(8))) short bf16x8;
typedef __attribute__((ext_vector_type(4))) float f32x4;

struct LevelParams {
    int res[NL];
    int hashed[NL];
    int uoff[NL];    // prefix sum of 512*r floats (per batch) into U  [i][cx][2] layout
    int soff[NL];    // prefix sum of (r+2) ints into stab
    int cwoff[NL];   // prefix sum of r*nck wave-units
    int nck[NL];     // ceil(r/64)
    int sumr;
    int nwaves;      // per batch
};

// ---- bf16 helpers (RNE) ----
__device__ __forceinline__ unsigned short f2bf(float f) {
    uint32_t u = __float_as_uint(f);
    return (unsigned short)((u + 0x7fffu + ((u >> 16) & 1u)) >> 16);
}
__device__ __forceinline__ float bflo(uint32_t u) { return __uint_as_float(u << 16); }
__device__ __forceinline__ float bfhi(uint32_t u) { return __uint_as_float(u & 0xffff0000u); }
__device__ __forceinline__ uint32_t packbf(float a, float b) {
    return (uint32_t)f2bf(a) | ((uint32_t)f2bf(b) << 16);
}

// ---- K0: styles[b][c] and dcoef[b][o] (tiny) ----
__global__ void k_styles(const float* __restrict__ s, const float* __restrict__ aw,
                         const float* __restrict__ ab, const float* __restrict__ cw,
                         float* __restrict__ styles, float* __restrict__ dcoef) {
    int t = threadIdx.x;
    int b = t >> 5, c = t & 31;
    const float* sv = s + b * SD;
    const float* wv = aw + c * SD;
    float acc = 0.f;
    for (int k = 0; k < SD; ++k) acc += sv[k] * wv[k];
    float st = acc * 0.04419417382415922f /* 1/sqrt(512) */ + ab[c];
    styles[b * CH + c] = st;
    __shared__ float st_sh[NB * CH];
    st_sh[b * CH + c] = st;
    __syncthreads();
    float d = 0.f;
    for (int i = 0; i < CH; ++i) {
        const float* w9 = cw + (c * CH + i) * 9;
        float ws = 0.f;
        #pragma unroll
        for (int k = 0; k < 9; ++k) ws += w9[k] * w9[k];
        float si = st_sh[b * CH + i];
        d += ws * si * si;
    }
    dcoef[b * CH + c] = rsqrtf(d + 1e-8f);
}

// ---- K_wtab: per-level (cell, frac) tables + lower-bound table S ----
// S[c] = #{i : cell(i) < c}  (== first i with cell(i) >= c, cells monotone)
__global__ void k_wtab(const float* __restrict__ coords, int* __restrict__ ctab,
                       float* __restrict__ ftab, int* __restrict__ stab,
                       LevelParams p) {
    int j = threadIdx.x;                       // 256
    float g = coords[2 * j];                   // x-coord of column j == y-coord of row j
    __shared__ int cs[256];
    for (int l = 0; l < NL; ++l) {
        int r = p.res[l];
        float px = g * (float)(r - 1);
        float fl = floorf(px);
        float f = px - fl;                     // frac from UNclipped floor
        int c = min((int)fl, r - 2);
        ctab[l * 256 + j] = c;
        ftab[l * 256 + j] = f;
        cs[j] = c;
        __syncthreads();
        for (int cc = j; cc <= r; cc += 256) {
            int cnt = 0;
            for (int i = 0; i < 256; ++i) cnt += (cs[i] < cc) ? 1 : 0;
            stab[p.soff[l] + cc] = cnt;
        }
        __syncthreads();
    }
}

// ---- K1: hash retrieve + modulation -> xm2 (pixel-contiguous, 16 u32/px) ----
template<int L>
__device__ __forceinline__ uint32_t lvl_fetch(const float* __restrict__ tb,
                                              const float* __restrict__ st,
                                              float cxv, float cyv,
                                              const LevelParams& p) {
    int r = p.res[L];                          // static index into kernarg
    float rm1 = (float)(r - 1);
    float px = cxv * rm1, py = cyv * rm1;
    float fxf = floorf(px), fyf = floorf(py);
    float fx = px - fxf, fy = py - fyf;
    int x0 = min((int)fxf, r - 2);
    int y0 = min((int)fyf, r - 2);
    uint32_t i00, i10, i01, i11;
    if (p.hashed[L]) {
        uint32_t hy0 = (uint32_t)y0 * PRIME, hy1 = (uint32_t)(y0 + 1) * PRIME;
        i00 = ((uint32_t)x0 ^ hy0) & (TD - 1);
        i10 = ((uint32_t)(x0 + 1) ^ hy0) & (TD - 1);
        i01 = ((uint32_t)x0 ^ hy1) & (TD - 1);
        i11 = ((uint32_t)(x0 + 1) ^ hy1) & (TD - 1);
    } else {
        i00 = (uint32_t)(y0 * r + x0); i10 = i00 + 1;
        i01 = i00 + r;                 i11 = i01 + 1;
    }
    const float* tl = tb + L * TD * 2;
    float2 g00 = *(const float2*)(tl + 2 * i00);
    float2 g10 = *(const float2*)(tl + 2 * i10);
    float2 g01 = *(const float2*)(tl + 2 * i01);
    float2 g11 = *(const float2*)(tl + 2 * i11);
    float w00 = (1.f - fx) * (1.f - fy), w10 = fx * (1.f - fy);
    float w01 = (1.f - fx) * fy,         w11 = fx * fy;
    float f0 = w00 * g00.x + w10 * g10.x + w01 * g01.x + w11 * g11.x;
    float f1 = w00 * g00.y + w10 * g10.y + w01 * g01.y + w11 * g11.y;
    return packbf(f0 * st[2 * L], f1 * st[2 * L + 1]);
}

template<int L0>
__device__ __forceinline__ uint4 fetch4(const float* __restrict__ tb,
                                        const float* __restrict__ st,
                                        float cxv, float cyv, const LevelParams& p) {
    uint4 v;
    v.x = lvl_fetch<L0 + 0>(tb, st, cxv, cyv, p);
    v.y = lvl_fetch<L0 + 1>(tb, st, cxv, cyv, p);
    v.z = lvl_fetch<L0 + 2>(tb, st, cxv, cyv, p);
    v.w = lvl_fetch<L0 + 3>(tb, st, cxv, cyv, p);
    return v;
}

__global__ void k_retrieve(const float* __restrict__ tables,
                           const float* __restrict__ coords,
                           const float* __restrict__ styles,
                           uint32_t* __restrict__ xm2, LevelParams p) {
    int wg = blockIdx.x;                       // 8192
    int b = wg & 7;                            // batch -> XCD pinning (L2 locality)
    int idx = (wg >> 3) * 256 + threadIdx.x;   // 0..262143
    int n = idx >> 2, q = idx & 3;
    float cxv = coords[2 * n];
    float cyv = coords[2 * n + 1];
    const float* tb = tables + (size_t)b * NL * TD * 2;
    const float* st = styles + b * CH;
    uint4 v;
    switch (q) {
        case 0: v = fetch4<0>(tb, st, cxv, cyv, p); break;
        case 1: v = fetch4<4>(tb, st, cxv, cyv, p); break;
        case 2: v = fetch4<8>(tb, st, cxv, cyv, p); break;
        default: v = fetch4<12>(tb, st, cxv, cyv, p); break;
    }
    *(uint4*)(xm2 + (size_t)b * NPIX * 16 + (size_t)idx * 4) = v;
}

// ---- K2: MFMA modulated 3x3 conv + demod + bias + lrelu*sqrt2 -> tokens ----
__global__ __launch_bounds__(256) void k_conv(
    const uint32_t* __restrict__ xm2, const float* __restrict__ cw,
    const float* __restrict__ cb, const float* __restrict__ dcoef,
    uint32_t* __restrict__ tokens) {
    __shared__ uint32_t xt[18 * 34 * 4 * 4];   // 39,168 B
    int b = blockIdx.z;
    int ty0 = blockIdx.y * 16, tx0 = blockIdx.x * 32;
    int tid = threadIdx.x;
    int lane = tid & 63, wv = tid >> 6;
    int npx = lane & 15, kg = lane >> 4;

    // A fragments: w[o][i=kg*8+j][tap]; o = ob*16 + (lane&15)
    bf16x8 wf[9][2];
    {
        union { bf16x8 v; unsigned short e[8]; } u;
        #pragma unroll
        for (int t = 0; t < 9; ++t) {
            #pragma unroll
            for (int ob = 0; ob < 2; ++ob) {
                int o = ob * 16 + npx;
                #pragma unroll
                for (int j = 0; j < 8; ++j)
                    u.e[j] = f2bf(cw[(o * 32 + kg * 8 + j) * 9 + t]);
                wf[t][ob] = u.v;
            }
        }
    }
    float dc[2][4], bs[2][4];
    #pragma unroll
    for (int ob = 0; ob < 2; ++ob)
        #pragma unroll
        for (int rg = 0; rg < 4; ++rg) {
            int oc = ob * 16 + kg * 4 + rg;
            dc[ob][rg] = dcoef[b * CH + oc];
            bs[ob][rg] = cb[oc];
        }

    for (int idx = tid; idx < 18 * 34 * 4; idx += 256) {
        int pl = idx >> 2, slot = idx & 3;
        int r = pl / 34, c = pl - r * 34;
        int gy = ty0 + r - 1, gx = tx0 + c - 1;
        int g = slot ^ (c & 3);
        uint4 v = make_uint4(0u, 0u, 0u, 0u);
        if ((unsigned)gy < 256u && (unsigned)gx < 256u)
            v = *(const uint4*)(xm2 + ((size_t)(b * NPIX) + gy * 256 + gx) * 16 + g * 4);
        *(uint4*)(xt + (size_t)idx * 4) = v;
    }
    __syncthreads();

    #pragma unroll 1
    for (int it = 0; it < 8; ++it) {
        int grp = it * 4 + wv;                 // 32 groups of 16 px
        int py_l = grp >> 1;
        int px_l = ((grp & 1) << 4) + npx;
        f32x4 a0 = {0.f, 0.f, 0.f, 0.f};
        f32x4 a1 = {0.f, 0.f, 0.f, 0.f};
        #pragma unroll
        for (int ky = 0; ky < 3; ++ky) {
            int rowb = (py_l + ky) * 34;
            #pragma unroll
            for (int kx = 0; kx < 3; ++kx) {
                int cc = px_l + kx;
                bf16x8 bf = *(const bf16x8*)(xt + (((rowb + cc) << 2) + (kg ^ (cc & 3))) * 4);
                a0 = __builtin_amdgcn_mfma_f32_16x16x32_bf16(wf[ky * 3 + kx][0], bf, a0, 0, 0, 0);
                a1 = __builtin_amdgcn_mfma_f32_16x16x32_bf16(wf[ky * 3 + kx][1], bf, a1, 0, 0, 0);
            }
        }
        int py = ty0 + py_l, px = tx0 + px_l;
        size_t pbase = (size_t)py * 256 + px;
        {
            float y0 = a0[0] * dc[0][0] + bs[0][0];
            float y1 = a0[1] * dc[0][1] + bs[0][1];
            float y2 = a0[2] * dc[0][2] + bs[0][2];
            float y3 = a0[3] * dc[0][3] + bs[0][3];
            y0 = (y0 > 0.f ? y0 : 0.2f * y0) * 1.4142135623730951f;
            y1 = (y1 > 0.f ? y1 : 0.2f * y1) * 1.4142135623730951f;
            y2 = (y2 > 0.f ? y2 : 0.2f * y2) * 1.4142135623730951f;
            y3 = (y3 > 0.f ? y3 : 0.2f * y3) * 1.4142135623730951f;
            int lp0 = kg * 2;
            tokens[((size_t)(b * NL + lp0)) * NPIX + pbase] = packbf(y0, y1);
            tokens[((size_t)(b * NL + lp0 + 1)) * NPIX + pbase] = packbf(y2, y3);
        }
        {
            float y0 = a1[0] * dc[1][0] + bs[1][0];
            float y1 = a1[1] * dc[1][1] + bs[1][1];
            float y2 = a1[2] * dc[1][2] + bs[1][2];
            float y3 = a1[3] * dc[1][3] + bs[1][3];
            y0 = (y0 > 0.f ? y0 : 0.2f * y0) * 1.4142135623730951f;
            y1 = (y1 > 0.f ? y1 : 0.2f * y1) * 1.4142135623730951f;
            y2 = (y2 > 0.f ? y2 : 0.2f * y2) * 1.4142135623730951f;
            y3 = (y3 > 0.f ? y3 : 0.2f * y3) * 1.4142135623730951f;
            int lp0 = 8 + kg * 2;
            tokens[((size_t)(b * NL + lp0)) * NPIX + pbase] = packbf(y0, y1);
            tokens[((size_t)(b * NL + lp0 + 1)) * NPIX + pbase] = packbf(y2, y3);
        }
    }
}

// ---- K3a: separable recon stage 1 — reduce over pixel columns j ----
// U layout: [b][l][i][cx][2] floats (transposed for stage-2 coalescing).
__global__ __launch_bounds__(128) void k_recon1(const uint32_t* __restrict__ tokens,
                                                const int* __restrict__ ctab,
                                                const float* __restrict__ ftab,
                                                float* __restrict__ U, LevelParams p) {
    int l = blockIdx.x, half = blockIdx.y, b = blockIdx.z;
    int i = half * 128 + threadIdx.x;
    int r = p.res[l];
    __shared__ int cs[256];
    __shared__ float fs[256];
    for (int t = threadIdx.x; t < 256; t += 128) {
        cs[t] = ctab[l * 256 + t];
        fs[t] = ftab[l * 256 + t];
    }
    __syncthreads();
    const uint32_t* trow = tokens + (size_t)(b * NL + l) * NPIX + i * 256;
    float* Ub = U + (size_t)b * (p.sumr * 512) + p.uoff[l] + (size_t)i * r * 2;
    int curc = 0;
    float aL0 = 0.f, aL1 = 0.f, aR0 = 0.f, aR1 = 0.f;
    #pragma unroll 4
    for (int j = 0; j < 256; j += 4) {
        uint4 tv = *(const uint4*)(trow + j);
        #pragma unroll
        for (int q = 0; q < 4; ++q) {
            uint32_t u = (&tv.x)[q];
            int c = cs[j + q];
            float f = fs[j + q];
            while (c != curc) {                // uniform across wave
                *(float2*)(Ub + curc * 2) = make_float2(aL0, aL1);
                aL0 = aR0; aL1 = aR1; aR0 = 0.f; aR1 = 0.f;
                ++curc;
            }
            float t0 = bflo(u), t1 = bfhi(u);
            float wA = 1.f - f;
            aL0 += wA * t0; aL1 += wA * t1;
            aR0 += f * t0;  aR1 += f * t1;
        }
    }
    *(float2*)(Ub + curc * 2) = make_float2(aL0, aL1);
    *(float2*)(Ub + (curc + 1) * 2) = make_float2(aR0, aR1);
}

// ---- K3b: stage 2 — wave per (level, cy, 64-wide cx chunk) ----
__global__ __launch_bounds__(256) void k_recon2(const float* __restrict__ U,
                                                const int* __restrict__ ctab,
                                                const float* __restrict__ ftab,
                                                const int* __restrict__ stab,
                                                float* __restrict__ R, LevelParams p) {
    int wid = blockIdx.x * 4 + (threadIdx.x >> 6);
    int lane = threadIdx.x & 63;
    int b = blockIdx.y;
    if (wid >= p.nwaves) return;
    int l = 0;
    #pragma unroll
    for (int q = 1; q < NL; ++q) if (wid >= p.cwoff[q]) l = q;
    int u = wid - p.cwoff[l];
    int r = p.res[l];
    int nck = p.nck[l];
    int cy = u / nck;
    int ck = u - cy * nck;
    int cx = ck * 64 + lane;
    bool valid = cx < r;
    const int* Sl = stab + p.soff[l];
    int ilo = (cy > 0) ? Sl[cy - 1] : 0;
    int ihi = Sl[min(cy + 1, r)] - 1;
    const float* Ub = U + (size_t)b * (p.sumr * 512) + p.uoff[l];
    const int* crow = ctab + l * 256;
    const float* frow = ftab + l * 256;
    float a0 = 0.f, a1 = 0.f;
    for (int i = ilo; i <= ihi; ++i) {
        int c = crow[i];
        float f = frow[i];
        float w = (c == cy) ? (1.f - f) : f;
        if (valid) {
            float2 uu = *(const float2*)(Ub + ((size_t)i * r + cx) * 2);
            a0 += w * uu.x;
            a1 += w * uu.y;
        }
    }
    if (!valid) return;
    float* Rbl = R + (size_t)(b * NL + l) * TD * 2;
    if (p.hashed[l]) {
        uint32_t h = ((uint32_t)cx ^ ((uint32_t)cy * PRIME)) & (TD - 1);
        atomicAdd(&Rbl[2 * h], a0);
        atomicAdd(&Rbl[2 * h + 1], a1);
    } else {
        *(float2*)(Rbl + 2 * (cy * r + cx)) = make_float2(a0, a1);
    }
}

// ---- K4: residual + LayerNorm(16384) -> FP32 out ----
__global__ void k_ln(const float* __restrict__ R, const float* __restrict__ inp,
                     float* __restrict__ out) {
    int row = blockIdx.x;                       // b*NL + l
    const float4* rv = (const float4*)(R + (size_t)row * 16384);
    const float4* iv = (const float4*)(inp + (size_t)row * 16384);
    int tid = threadIdx.x;
    float sum = 0.f, ssq = 0.f;
    for (int k = tid; k < 4096; k += 256) {
        float4 a = rv[k], c = iv[k];
        float x0 = a.x + c.x, x1 = a.y + c.y, x2 = a.z + c.z, x3 = a.w + c.w;
        sum += x0 + x1 + x2 + x3;
        ssq += x0 * x0 + x1 * x1 + x2 * x2 + x3 * x3;
    }
    #pragma unroll
    for (int off = 32; off > 0; off >>= 1) {
        sum += __shfl_xor(sum, off, 64);
        ssq += __shfl_xor(ssq, off, 64);
    }
    __shared__ float red[8];
    int w = tid >> 6;
    if ((tid & 63) == 0) { red[w * 2] = sum; red[w * 2 + 1] = ssq; }
    __syncthreads();
    sum = red[0] + red[2] + red[4] + red[6];
    ssq = red[1] + red[3] + red[5] + red[7];
    float mu = sum * (1.f / 16384.f);
    float var = ssq * (1.f / 16384.f) - mu * mu;
    float inv = rsqrtf(var + 1e-5f);
    float4* ob = (float4*)(out + (size_t)row * 16384);
    for (int k = tid; k < 4096; k += 256) {
        float4 a = rv[k], c = iv[k];
        float4 o4;
        o4.x = (a.x + c.x - mu) * inv;
        o4.y = (a.y + c.y - mu) * inv;
        o4.z = (a.z + c.z - mu) * inv;
        o4.w = (a.w + c.w - mu) * inv;
        ob[k] = o4;
    }
}

extern "C" void kernel_launch(void* const* d_in, const int* in_sizes, int n_in,
                              void* d_out, int out_size, void* d_ws, size_t ws_size,
                              hipStream_t stream) {
    const float* inputs = (const float*)d_in[0];
    const float* s      = (const float*)d_in[1];
    const float* coords = (const float*)d_in[2];
    const float* aw     = (const float*)d_in[3];
    const float* ab     = (const float*)d_in[4];
    const float* cw     = (const float*)d_in[5];
    const float* cb     = (const float*)d_in[6];

    char* ws = (char*)d_ws;
    uint32_t* xm2    = (uint32_t*)(ws);                 // 33,554,432 B (reused as U after conv)
    uint32_t* tokens = (uint32_t*)(ws + 33554432);      // 33,554,432 B
    float*    R      = (float*)(ws + 67108864);         //  8,388,608 B
    float*    styles = (float*)(ws + 75497472);         //  1 KB
    float*    dcoef  = (float*)(ws + 75498496);         //  1 KB
    int*      ctab   = (int*)(ws + 75499520);           // 16 KB
    float*    ftab   = (float*)(ws + 75515904);         // 16 KB
    int*      stab   = (int*)(ws + 75532288);           // ~6 KB

    // RES_LIST exactly as numpy computes it (double libm ops).
    LevelParams p;
    double bb = exp((log(256.0) - log(16.0)) / 15.0);
    int uoff = 0, soff = 0, cwoff = 0;
    for (int l = 0; l < NL; ++l) {
        int r = (int)floor(16.0 * pow(bb, (double)l));
        p.res[l] = r;
        p.hashed[l] = (r * r > TD) ? 1 : 0;
        p.uoff[l] = uoff;
        p.soff[l] = soff;
        p.cwoff[l] = cwoff;
        int nck = (r + 63) >> 6;
        p.nck[l] = nck;
        uoff += r * 512;
        soff += r + 2;
        cwoff += r * nck;
    }
    p.sumr = uoff / 512;
    p.nwaves = cwoff;

    hipMemsetAsync(R, 0, (size_t)NB * NL * TD * 2 * sizeof(float), stream);
    hipLaunchKernelGGL(k_styles, dim3(1), dim3(256), 0, stream, s, aw, ab, cw, styles, dcoef);
    hipLaunchKernelGGL(k_wtab, dim3(1), dim3(256), 0, stream, coords, ctab, ftab, stab, p);
    hipLaunchKernelGGL(k_retrieve, dim3(8192), dim3(256), 0, stream,
                       inputs, coords, styles, xm2, p);
    hipLaunchKernelGGL(k_conv, dim3(8, 16, NB), dim3(256), 0, stream,
                       xm2, cw, cb, dcoef, tokens);
    float* U = (float*)xm2;                             // xm2 dead after k_conv
    hipLaunchKernelGGL(k_recon1, dim3(NL, 2, NB), dim3(128), 0, stream,
                       tokens, ctab, ftab, U, p);
    hipLaunchKernelGGL(k_recon2, dim3((p.nwaves + 3) / 4, NB), dim3(256), 0, stream,
                       U, ctab, ftab, stab, R, p);
    hipLaunchKernelGGL(k_ln, dim3(NB * NL), dim3(256), 0, stream,
                       R, inputs, (float*)d_out);
}

// Round 6
// 213.719 us; speedup vs baseline: 2.7321x; 1.2186x over previous
//
#include <hip/hip_runtime.h>
#include <cmath>
#include <cstdint>

#define NB 8
#define NL 16
#define TD 8192
#define NPIX 65536
#define CH 32
#define SD 512

static constexpr uint32_t PRIME = 2654435761u;

typedef __attribute__((ext_vector_type(8))) short bf16x8;
typedef __attribute__((ext_vector_type(4))) float f32x4;

// per-level corner-tile capacities for a 16x32 tile (+halo): worst case +margin
static constexpr int cNCX[16] = {5,6,6,7,8,9,10,11,12,14,16,19,22,26,31,36};
static constexpr int cNCY[16] = {4,5,5,5,6,6,7,7,8,9,10,12,13,15,18,20};
static constexpr int CTOFF[17] = {0,20,50,80,115,163,217,287,364,460,586,746,974,1260,1650,2208,2928};

struct LevelParams {
    int res[NL];
    int hashed[NL];
    int uoff[NL];    // prefix of 512*r floats (per batch) into U  [i][cx][2]
    int soff[NL];    // prefix of (r+2) ints into stab
    int cwoff[NL];   // recon2 wave prefix (r*nck)
    int r1off[NL];   // recon1 wave prefix (256*nck)
    int nck[NL];     // ceil(r/64)
    int sumr;
    int nwaves;      // recon2 waves per batch
    int n1waves;     // recon1 waves per batch
};

// ---- bf16 helpers (RNE) ----
__device__ __forceinline__ unsigned short f2bf(float f) {
    uint32_t u = __float_as_uint(f);
    return (unsigned short)((u + 0x7fffu + ((u >> 16) & 1u)) >> 16);
}
__device__ __forceinline__ float bflo(uint32_t u) { return __uint_as_float(u << 16); }
__device__ __forceinline__ float bfhi(uint32_t u) { return __uint_as_float(u & 0xffff0000u); }
__device__ __forceinline__ uint32_t packbf(float a, float b) {
    return (uint32_t)f2bf(a) | ((uint32_t)f2bf(b) << 16);
}

// ---- K0: styles[b][c] and dcoef[b][o] ----
__global__ void k_styles(const float* __restrict__ s, const float* __restrict__ aw,
                         const float* __restrict__ ab, const float* __restrict__ cw,
                         float* __restrict__ styles, float* __restrict__ dcoef) {
    int t = threadIdx.x;
    int b = t >> 5, c = t & 31;
    const float* sv = s + b * SD;
    const float* wv = aw + c * SD;
    float acc = 0.f;
    for (int k = 0; k < SD; ++k) acc += sv[k] * wv[k];
    float st = acc * 0.04419417382415922f + ab[c];
    styles[b * CH + c] = st;
    __shared__ float st_sh[NB * CH];
    st_sh[b * CH + c] = st;
    __syncthreads();
    float d = 0.f;
    for (int i = 0; i < CH; ++i) {
        const float* w9 = cw + (c * CH + i) * 9;
        float ws = 0.f;
        #pragma unroll
        for (int k = 0; k < 9; ++k) ws += w9[k] * w9[k];
        float si = st_sh[b * CH + i];
        d += ws * si * si;
    }
    dcoef[b * CH + c] = rsqrtf(d + 1e-8f);
}

// ---- K_wtab: per-level (cell, frac) tables + lower-bound table S (block per level) ----
__global__ void k_wtab(const float* __restrict__ coords, int* __restrict__ ctab,
                       float* __restrict__ ftab, int* __restrict__ stab,
                       LevelParams p) {
    int l = blockIdx.x;
    int j = threadIdx.x;
    int r = p.res[l];
    float g = coords[2 * j];                   // x-coord of col j == y-coord of row j
    float px = g * (float)(r - 1);
    float fl = floorf(px);
    float f = px - fl;
    int c = min((int)fl, r - 2);
    ctab[l * 256 + j] = c;
    ftab[l * 256 + j] = f;
    __shared__ int cs[256];
    cs[j] = c;
    __syncthreads();
    for (int cc = j; cc <= r; cc += 256) {
        int cnt = 0;
        for (int i = 0; i < 256; ++i) cnt += (cs[i] < cc) ? 1 : 0;
        stab[p.soff[l] + cc] = cnt;
    }
}

// ---- fused retrieve feature from LDS corner tiles ----
__device__ __forceinline__ uint32_t feat1_impl(int L, int pcol, int prow,
                                               const float2* col2, const float2* row2,
                                               const float2* ctile, int ncxL, int ctoffL) {
    float2 cv = col2[L * 34 + pcol];
    float2 rv = row2[L * 18 + prow];
    int cxr = __float_as_int(cv.x);
    float fx = cv.y;
    int cyr = __float_as_int(rv.x);
    float fy = rv.y;
    const float2* ct = ctile + ctoffL + cyr * ncxL + cxr;
    float2 g00 = ct[0], g10 = ct[1];
    float2 g01 = ct[ncxL], g11 = ct[ncxL + 1];
    float w00 = (1.f - fx) * (1.f - fy), w10 = fx * (1.f - fy);
    float w01 = (1.f - fx) * fy,         w11 = fx * fy;
    float f0 = w00 * g00.x + w10 * g10.x + w01 * g01.x + w11 * g11.x;
    float f1 = w00 * g00.y + w10 * g10.y + w01 * g01.y + w11 * g11.y;
    return packbf(f0, f1);
}

template<int L0>
__device__ __forceinline__ uint4 feat4(int pcol, int prow, const float2* col2,
                                       const float2* row2, const float2* ctile) {
    uint4 v;
    v.x = feat1_impl(L0 + 0, pcol, prow, col2, row2, ctile, cNCX[L0 + 0], CTOFF[L0 + 0]);
    v.y = feat1_impl(L0 + 1, pcol, prow, col2, row2, ctile, cNCX[L0 + 1], CTOFF[L0 + 1]);
    v.z = feat1_impl(L0 + 2, pcol, prow, col2, row2, ctile, cNCX[L0 + 2], CTOFF[L0 + 2]);
    v.w = feat1_impl(L0 + 3, pcol, prow, col2, row2, ctile, cNCX[L0 + 3], CTOFF[L0 + 3]);
    return v;
}

// ---- K2: FUSED hash-retrieve + modulation + MFMA 3x3 conv + demod/bias/lrelu ----
// block = one 16x32 output tile of one batch; b = bid&7 (XCD pinning).
__global__ __launch_bounds__(256) void k_conv(
    const float* __restrict__ tables, const int* __restrict__ ctab,
    const float* __restrict__ ftab, const float* __restrict__ styles,
    const float* __restrict__ cw, const float* __restrict__ cb,
    const float* __restrict__ dcoef, uint32_t* __restrict__ tokens,
    LevelParams p) {
    __shared__ uint32_t xt[18 * 34 * 16];      // 39168 B feature tile (bf16x2 chunks)
    __shared__ float2 ctile[2928];             // 23424 B deduped style-premod corners
    __shared__ float2 col2[NL * 34];           // (cell-rel, frac) per halo col
    __shared__ float2 row2[NL * 18];           // per halo row
    __shared__ int cxbase[NL], cybase[NL], ncxA[NL], ncyA[NL];

    int bid = blockIdx.x;
    int b = bid & 7;
    int t = bid >> 3;
    int tx0 = (t & 7) * 32, ty0 = (t >> 3) * 16;
    int tid = threadIdx.x;
    int lane = tid & 63, wv = tid >> 6;
    int npx = lane & 15, kg = lane >> 4;
    const float* tb = tables + (size_t)b * NL * TD * 2;

    // A fragments (weights) while staging proceeds
    bf16x8 wf[9][2];
    {
        union { bf16x8 v; unsigned short e[8]; } u;
        #pragma unroll
        for (int tp = 0; tp < 9; ++tp)
            #pragma unroll
            for (int ob = 0; ob < 2; ++ob) {
                int o = ob * 16 + npx;
                #pragma unroll
                for (int j = 0; j < 8; ++j)
                    u.e[j] = f2bf(cw[(o * 32 + kg * 8 + j) * 9 + tp]);
                wf[tp][ob] = u.v;
            }
    }
    float dc[2][4], bs[2][4];
    #pragma unroll
    for (int ob = 0; ob < 2; ++ob)
        #pragma unroll
        for (int rg = 0; rg < 4; ++rg) {
            int oc = ob * 16 + kg * 4 + rg;
            dc[ob][rg] = dcoef[b * CH + oc];
            bs[ob][rg] = cb[oc];
        }

    // ---- phase 0a: col/row (cell,frac) tables + extents ----
    for (int u0 = tid; u0 < NL * 64; u0 += 256) {
        int l = u0 >> 6, pos = u0 & 63;
        if (pos < 34) {
            int gx = tx0 - 1 + pos;
            if ((unsigned)gx < 256u) {
                int base = ctab[l * 256 + max(tx0 - 1, 0)];
                col2[l * 34 + pos] = make_float2(
                    __int_as_float(ctab[l * 256 + gx] - base), ftab[l * 256 + gx]);
            }
        } else if (pos < 52) {
            int pr = pos - 34;
            int gy = ty0 - 1 + pr;
            if ((unsigned)gy < 256u) {
                int base = ctab[l * 256 + max(ty0 - 1, 0)];
                row2[l * 18 + pr] = make_float2(
                    __int_as_float(ctab[l * 256 + gy] - base), ftab[l * 256 + gy]);
            }
        } else if (pos == 52) {
            int cxb = ctab[l * 256 + max(tx0 - 1, 0)];
            int cyb = ctab[l * 256 + max(ty0 - 1, 0)];
            cxbase[l] = cxb;
            cybase[l] = cyb;
            ncxA[l] = ctab[l * 256 + min(tx0 + 32, 255)] - cxb + 2;
            ncyA[l] = ctab[l * 256 + min(ty0 + 16, 255)] - cyb + 2;
        }
    }
    __syncthreads();

    // ---- phase 0b: gather deduped corners, premultiply style ----
    #pragma unroll
    for (int l = 0; l < NL; ++l) {
        const int NCXl = cNCX[l];
        const int CAP = cNCX[l] * cNCY[l];
        for (int u2 = tid; u2 < CAP; u2 += 256) {
            int sy = u2 / NCXl;
            int sx = u2 - sy * NCXl;
            if (sx < ncxA[l] && sy < ncyA[l]) {
                int ax = cxbase[l] + sx, ay = cybase[l] + sy;
                int r = p.res[l];
                uint32_t idx = p.hashed[l]
                    ? (((uint32_t)ax ^ ((uint32_t)ay * PRIME)) & (TD - 1))
                    : (uint32_t)(ay * r + ax);
                float2 g = *(const float2*)(tb + (size_t)l * TD * 2 + 2 * idx);
                float s0 = styles[b * CH + 2 * l], s1 = styles[b * CH + 2 * l + 1];
                ctile[CTOFF[l] + sy * NCXl + sx] = make_float2(g.x * s0, g.y * s1);
            }
        }
    }
    __syncthreads();

    // ---- phase 1: per-pixel bilinear from LDS corners -> xt (swizzled) ----
    for (int idx = tid; idx < 612 * 4; idx += 256) {
        int pl = idx >> 2, q = idx & 3;
        int rr = pl / 34, cc = pl - rr * 34;
        int gy = ty0 + rr - 1, gx = tx0 + cc - 1;
        uint4 v = make_uint4(0u, 0u, 0u, 0u);
        if ((unsigned)gy < 256u && (unsigned)gx < 256u) {
            switch (q) {
                case 0: v = feat4<0>(cc, rr, col2, row2, ctile); break;
                case 1: v = feat4<4>(cc, rr, col2, row2, ctile); break;
                case 2: v = feat4<8>(cc, rr, col2, row2, ctile); break;
                default: v = feat4<12>(cc, rr, col2, row2, ctile); break;
            }
        }
        int slot = q ^ (cc & 3);
        *(uint4*)(xt + (size_t)(pl * 4 + slot) * 4) = v;
    }
    __syncthreads();

    // ---- phase 2: MFMA conv ----
    #pragma unroll 1
    for (int it = 0; it < 8; ++it) {
        int grp = it * 4 + wv;
        int py_l = grp >> 1;
        int px_l = ((grp & 1) << 4) + npx;
        f32x4 a0 = {0.f, 0.f, 0.f, 0.f};
        f32x4 a1 = {0.f, 0.f, 0.f, 0.f};
        #pragma unroll
        for (int ky = 0; ky < 3; ++ky) {
            int rowb = (py_l + ky) * 34;
            #pragma unroll
            for (int kx = 0; kx < 3; ++kx) {
                int cc = px_l + kx;
                bf16x8 bf = *(const bf16x8*)(xt + (((rowb + cc) << 2) + (kg ^ (cc & 3))) * 4);
                a0 = __builtin_amdgcn_mfma_f32_16x16x32_bf16(wf[ky * 3 + kx][0], bf, a0, 0, 0, 0);
                a1 = __builtin_amdgcn_mfma_f32_16x16x32_bf16(wf[ky * 3 + kx][1], bf, a1, 0, 0, 0);
            }
        }
        int py = ty0 + py_l, px = tx0 + px_l;
        size_t pbase = (size_t)py * 256 + px;
        {
            float y0 = a0[0] * dc[0][0] + bs[0][0];
            float y1 = a0[1] * dc[0][1] + bs[0][1];
            float y2 = a0[2] * dc[0][2] + bs[0][2];
            float y3 = a0[3] * dc[0][3] + bs[0][3];
            y0 = (y0 > 0.f ? y0 : 0.2f * y0) * 1.4142135623730951f;
            y1 = (y1 > 0.f ? y1 : 0.2f * y1) * 1.4142135623730951f;
            y2 = (y2 > 0.f ? y2 : 0.2f * y2) * 1.4142135623730951f;
            y3 = (y3 > 0.f ? y3 : 0.2f * y3) * 1.4142135623730951f;
            int lp0 = kg * 2;
            tokens[((size_t)(b * NL + lp0)) * NPIX + pbase] = packbf(y0, y1);
            tokens[((size_t)(b * NL + lp0 + 1)) * NPIX + pbase] = packbf(y2, y3);
        }
        {
            float y0 = a1[0] * dc[1][0] + bs[1][0];
            float y1 = a1[1] * dc[1][1] + bs[1][1];
            float y2 = a1[2] * dc[1][2] + bs[1][2];
            float y3 = a1[3] * dc[1][3] + bs[1][3];
            y0 = (y0 > 0.f ? y0 : 0.2f * y0) * 1.4142135623730951f;
            y1 = (y1 > 0.f ? y1 : 0.2f * y1) * 1.4142135623730951f;
            y2 = (y2 > 0.f ? y2 : 0.2f * y2) * 1.4142135623730951f;
            y3 = (y3 > 0.f ? y3 : 0.2f * y3) * 1.4142135623730951f;
            int lp0 = 8 + kg * 2;
            tokens[((size_t)(b * NL + lp0)) * NPIX + pbase] = packbf(y0, y1);
            tokens[((size_t)(b * NL + lp0 + 1)) * NPIX + pbase] = packbf(y2, y3);
        }
    }
}

// ---- K3a: recon stage 1, direct form — wave per (l, row i, 64-wide cx chunk) ----
// U[b][l][i][cx][2] = sum_j w(j,cx) * T[i][j], j in stab window (j ascending, bit-exact)
__global__ __launch_bounds__(256) void k_recon1(const uint32_t* __restrict__ tokens,
                                                const int* __restrict__ ctab,
                                                const float* __restrict__ ftab,
                                                const int* __restrict__ stab,
                                                float* __restrict__ U, LevelParams p) {
    int wid = blockIdx.x * 4 + (threadIdx.x >> 6);
    int lane = threadIdx.x & 63;
    int b = blockIdx.y;
    if (wid >= p.n1waves) return;
    int l = 0;
    #pragma unroll
    for (int q = 1; q < NL; ++q) if (wid >= p.r1off[q]) l = q;
    int u = wid - p.r1off[l];
    int nck = p.nck[l];
    int i = u / nck;
    int ck = u - i * nck;
    int r = p.res[l];
    int cx = ck * 64 + lane;
    bool valid = cx < r;
    const int* Sl = stab + p.soff[l];
    int jlo = 1, jhi = 0;
    if (valid) {
        jlo = (cx > 0) ? Sl[cx - 1] : 0;
        jhi = Sl[min(cx + 1, r)] - 1;
    }
    const uint32_t* trow = tokens + (size_t)(b * NL + l) * NPIX + i * 256;
    const int* crow = ctab + l * 256;
    const float* frow = ftab + l * 256;
    float a0 = 0.f, a1 = 0.f;
    for (int j = jlo; j <= jhi; ++j) {
        int c = crow[j];
        float f = frow[j];
        float w = (c == cx) ? (1.f - f) : f;
        uint32_t tv = trow[j];
        a0 += w * bflo(tv);
        a1 += w * bfhi(tv);
    }
    if (valid)
        *(float2*)(U + (size_t)b * (p.sumr * 512) + p.uoff[l] + ((size_t)i * r + cx) * 2)
            = make_float2(a0, a1);
}

// ---- K3b: recon stage 2 — wave per (level, cy, 64-wide cx chunk) ----
__global__ __launch_bounds__(256) void k_recon2(const float* __restrict__ U,
                                                const int* __restrict__ ctab,
                                                const float* __restrict__ ftab,
                                                const int* __restrict__ stab,
                                                float* __restrict__ R, LevelParams p) {
    int wid = blockIdx.x * 4 + (threadIdx.x >> 6);
    int lane = threadIdx.x & 63;
    int b = blockIdx.y;
    if (wid >= p.nwaves) return;
    int l = 0;
    #pragma unroll
    for (int q = 1; q < NL; ++q) if (wid >= p.cwoff[q]) l = q;
    int u = wid - p.cwoff[l];
    int r = p.res[l];
    int nck = p.nck[l];
    int cy = u / nck;
    int ck = u - cy * nck;
    int cx = ck * 64 + lane;
    bool valid = cx < r;
    const int* Sl = stab + p.soff[l];
    int ilo = (cy > 0) ? Sl[cy - 1] : 0;
    int ihi = Sl[min(cy + 1, r)] - 1;
    const float* Ub = U + (size_t)b * (p.sumr * 512) + p.uoff[l];
    const int* crow = ctab + l * 256;
    const float* frow = ftab + l * 256;
    float a0 = 0.f, a1 = 0.f;
    for (int i = ilo; i <= ihi; ++i) {
        int c = crow[i];
        float f = frow[i];
        float w = (c == cy) ? (1.f - f) : f;
        if (valid) {
            float2 uu = *(const float2*)(Ub + ((size_t)i * r + cx) * 2);
            a0 += w * uu.x;
            a1 += w * uu.y;
        }
    }
    if (!valid) return;
    float* Rbl = R + (size_t)(b * NL + l) * TD * 2;
    if (p.hashed[l]) {
        uint32_t h = ((uint32_t)cx ^ ((uint32_t)cy * PRIME)) & (TD - 1);
        atomicAdd(&Rbl[2 * h], a0);
        atomicAdd(&Rbl[2 * h + 1], a1);
    } else {
        *(float2*)(Rbl + 2 * (cy * r + cx)) = make_float2(a0, a1);
    }
}

// ---- K4: residual + LayerNorm(16384) -> FP32 out ----
__global__ void k_ln(const float* __restrict__ R, const float* __restrict__ inp,
                     float* __restrict__ out) {
    int row = blockIdx.x;                       // b*NL + l
    const float4* rv = (const float4*)(R + (size_t)row * 16384);
    const float4* iv = (const float4*)(inp + (size_t)row * 16384);
    int tid = threadIdx.x;
    float sum = 0.f, ssq = 0.f;
    for (int k = tid; k < 4096; k += 256) {
        float4 a = rv[k], c = iv[k];
        float x0 = a.x + c.x, x1 = a.y + c.y, x2 = a.z + c.z, x3 = a.w + c.w;
        sum += x0 + x1 + x2 + x3;
        ssq += x0 * x0 + x1 * x1 + x2 * x2 + x3 * x3;
    }
    #pragma unroll
    for (int off = 32; off > 0; off >>= 1) {
        sum += __shfl_xor(sum, off, 64);
        ssq += __shfl_xor(ssq, off, 64);
    }
    __shared__ float red[8];
    int w = tid >> 6;
    if ((tid & 63) == 0) { red[w * 2] = sum; red[w * 2 + 1] = ssq; }
    __syncthreads();
    sum = red[0] + red[2] + red[4] + red[6];
    ssq = red[1] + red[3] + red[5] + red[7];
    float mu = sum * (1.f / 16384.f);
    float var = ssq * (1.f / 16384.f) - mu * mu;
    float inv = rsqrtf(var + 1e-5f);
    float4* ob = (float4*)(out + (size_t)row * 16384);
    for (int k = tid; k < 4096; k += 256) {
        float4 a = rv[k], c = iv[k];
        float4 o4;
        o4.x = (a.x + c.x - mu) * inv;
        o4.y = (a.y + c.y - mu) * inv;
        o4.z = (a.z + c.z - mu) * inv;
        o4.w = (a.w + c.w - mu) * inv;
        ob[k] = o4;
    }
}

extern "C" void kernel_launch(void* const* d_in, const int* in_sizes, int n_in,
                              void* d_out, int out_size, void* d_ws, size_t ws_size,
                              hipStream_t stream) {
    const float* inputs = (const float*)d_in[0];
    const float* s      = (const float*)d_in[1];
    const float* coords = (const float*)d_in[2];
    const float* aw     = (const float*)d_in[3];
    const float* ab     = (const float*)d_in[4];
    const float* cw     = (const float*)d_in[5];
    const float* cb     = (const float*)d_in[6];

    char* ws = (char*)d_ws;
    float*    U      = (float*)(ws);                    // 23.4 MB used of 33.5 MB slot
    uint32_t* tokens = (uint32_t*)(ws + 33554432);      // 33,554,432 B
    float*    R      = (float*)(ws + 67108864);         //  8,388,608 B
    float*    styles = (float*)(ws + 75497472);
    float*    dcoef  = (float*)(ws + 75498496);
    int*      ctab   = (int*)(ws + 75499520);           // 16 KB
    float*    ftab   = (float*)(ws + 75515904);         // 16 KB
    int*      stab   = (int*)(ws + 75532288);           // ~6 KB

    // RES_LIST exactly as numpy computes it (double libm ops).
    LevelParams p;
    double bb = exp((log(256.0) - log(16.0)) / 15.0);
    int uoff = 0, soff = 0, cwoff = 0, r1off = 0;
    for (int l = 0; l < NL; ++l) {
        int r = (int)floor(16.0 * pow(bb, (double)l));
        p.res[l] = r;
        p.hashed[l] = (r * r > TD) ? 1 : 0;
        p.uoff[l] = uoff;
        p.soff[l] = soff;
        p.cwoff[l] = cwoff;
        p.r1off[l] = r1off;
        int nck = (r + 63) >> 6;
        p.nck[l] = nck;
        uoff += r * 512;
        soff += r + 2;
        cwoff += r * nck;
        r1off += 256 * nck;
    }
    p.sumr = uoff / 512;
    p.nwaves = cwoff;
    p.n1waves = r1off;

    hipMemsetAsync(R, 0, (size_t)NB * NL * TD * 2 * sizeof(float), stream);
    hipLaunchKernelGGL(k_styles, dim3(1), dim3(256), 0, stream, s, aw, ab, cw, styles, dcoef);
    hipLaunchKernelGGL(k_wtab, dim3(NL), dim3(256), 0, stream, coords, ctab, ftab, stab, p);
    hipLaunchKernelGGL(k_conv, dim3(1024), dim3(256), 0, stream,
                       inputs, ctab, ftab, styles, cw, cb, dcoef, tokens, p);
    hipLaunchKernelGGL(k_recon1, dim3((p.n1waves + 3) / 4, NB), dim3(256), 0, stream,
                       tokens, ctab, ftab, stab, U, p);
    hipLaunchKernelGGL(k_recon2, dim3((p.nwaves + 3) / 4, NB), dim3(256), 0, stream,
                       U, ctab, ftab, stab, R, p);
    hipLaunchKernelGGL(k_ln, dim3(NB * NL), dim3(256), 0, stream,
                       R, inputs, (float*)d_out);
}

// Round 7
// 169.521 us; speedup vs baseline: 3.4444x; 1.2607x over previous
//
#include <hip/hip_runtime.h>
#include <cmath>
#include <cstdint>

#define NB 8
#define NL 16
#define TD 8192
#define NPIX 65536
#define CH 32
#define SD 512

static constexpr uint32_t PRIME = 2654435761u;

typedef __attribute__((ext_vector_type(8))) short bf16x8;
typedef __attribute__((ext_vector_type(4))) float f32x4;

// per-level corner-tile capacities for a 16x32 tile (+halo): worst case +margin
static constexpr int cNCX[16] = {5,6,6,7,8,9,10,11,12,14,16,19,22,26,31,36};
static constexpr int cNCY[16] = {4,5,5,5,6,6,7,7,8,9,10,12,13,15,18,20};
static constexpr int CTOFF[17] = {0,20,50,80,115,163,217,287,364,460,586,746,974,1260,1650,2208,2928};

struct LevelParams {
    int res[NL];
    int hashed[NL];
    int uoff[NL];    // prefix of 512*r floats (per batch) into U  [i][cx][2]
    int soff[NL];    // prefix of (r+2) ints into stab
    int cwoff[NL];   // recon2 wave prefix (r*nck)
    int r1off[NL];   // recon1 wave prefix (256*nck)
    int nck[NL];     // ceil(r/64)
    int sumr;
    int nwaves;      // recon2 waves per batch
    int n1waves;     // recon1 waves per batch
};

// ---- bf16 helpers (RNE) ----
__device__ __forceinline__ unsigned short f2bf(float f) {
    uint32_t u = __float_as_uint(f);
    return (unsigned short)((u + 0x7fffu + ((u >> 16) & 1u)) >> 16);
}
__device__ __forceinline__ float bflo(uint32_t u) { return __uint_as_float(u << 16); }
__device__ __forceinline__ float bfhi(uint32_t u) { return __uint_as_float(u & 0xffff0000u); }
__device__ __forceinline__ uint32_t packbf(float a, float b) {
    return (uint32_t)f2bf(a) | ((uint32_t)f2bf(b) << 16);
}

// ---- K0: styles[b][c] and dcoef[b][o]; block per batch ----
__global__ __launch_bounds__(256) void k_styles(
    const float* __restrict__ s, const float* __restrict__ aw,
    const float* __restrict__ ab, const float* __restrict__ cw,
    float* __restrict__ styles, float* __restrict__ dcoef) {
    int b = blockIdx.x;
    int t = threadIdx.x;
    int c = t >> 3, part = t & 7;               // 32 ch x 8 parts
    const float* sv = s + b * SD + part * 64;
    const float* wv = aw + c * SD + part * 64;
    float acc = 0.f;
    #pragma unroll 8
    for (int k = 0; k < 64; ++k) acc += sv[k] * wv[k];
    acc += __shfl_xor(acc, 1, 64);
    acc += __shfl_xor(acc, 2, 64);
    acc += __shfl_xor(acc, 4, 64);
    __shared__ float st_sh[CH];
    if (part == 0) {
        float st = acc * 0.04419417382415922f /* 1/sqrt(512) */ + ab[c];
        styles[b * CH + c] = st;
        st_sh[c] = st;
    }
    __syncthreads();
    if (t < CH) {
        float d = 0.f;
        for (int i = 0; i < CH; ++i) {
            const float* w9 = cw + (t * CH + i) * 9;
            float ws = 0.f;
            #pragma unroll
            for (int k = 0; k < 9; ++k) ws += w9[k] * w9[k];
            float si = st_sh[i];
            d += ws * si * si;
        }
        dcoef[b * CH + t] = rsqrtf(d + 1e-8f);
    }
}

// ---- K_wtab: per-level (cell, frac) tables + fused cftab + lower-bound S ----
__global__ void k_wtab(const float* __restrict__ coords, int* __restrict__ ctab,
                       float* __restrict__ ftab, float2* __restrict__ cftab,
                       int* __restrict__ stab, LevelParams p) {
    int l = blockIdx.x;
    int j = threadIdx.x;
    int r = p.res[l];
    float g = coords[2 * j];                   // x-coord of col j == y-coord of row j
    float px = g * (float)(r - 1);
    float fl = floorf(px);
    float f = px - fl;
    int c = min((int)fl, r - 2);
    ctab[l * 256 + j] = c;
    ftab[l * 256 + j] = f;
    cftab[l * 256 + j] = make_float2(__int_as_float(c), f);
    __shared__ int cs[256];
    cs[j] = c;
    __syncthreads();
    for (int cc = j; cc <= r; cc += 256) {
        int cnt = 0;
        for (int i = 0; i < 256; ++i) cnt += (cs[i] < cc) ? 1 : 0;
        stab[p.soff[l] + cc] = cnt;
    }
}

// ---- fused retrieve feature from bf16-packed LDS corner tiles ----
template<int L>
__device__ __forceinline__ uint32_t feat1(int gx, int gy,
                                          const float2* __restrict__ cftab,
                                          const uint32_t* ctile,
                                          int cxbL, int cybL) {
    float2 cv = cftab[L * 256 + gx];
    float2 rv = cftab[L * 256 + gy];
    int cxr = __float_as_int(cv.x) - cxbL;
    int cyr = __float_as_int(rv.x) - cybL;
    float fx = cv.y, fy = rv.y;
    int a = CTOFF[L] + cyr * cNCX[L] + cxr;
    uint32_t c00 = ctile[a], c10 = ctile[a + 1];
    uint32_t c01 = ctile[a + cNCX[L]], c11 = ctile[a + cNCX[L] + 1];
    float w00 = (1.f - fx) * (1.f - fy), w10 = fx * (1.f - fy);
    float w01 = (1.f - fx) * fy,         w11 = fx * fy;
    float f0 = w00 * bflo(c00) + w10 * bflo(c10) + w01 * bflo(c01) + w11 * bflo(c11);
    float f1 = w00 * bfhi(c00) + w10 * bfhi(c10) + w01 * bfhi(c01) + w11 * bfhi(c11);
    return packbf(f0, f1);
}

// ---- phase 1 body for one level-group (wave-uniform, no divergence) ----
template<int L0>
__device__ __forceinline__ void phase1(int lane, int tx0, int ty0,
                                       const float2* __restrict__ cftab,
                                       const uint32_t* ctile,
                                       const int* cxbase, const int* cybase,
                                       uint32_t* xt) {
    int cxb0 = cxbase[L0 + 0], cyb0 = cybase[L0 + 0];
    int cxb1 = cxbase[L0 + 1], cyb1 = cybase[L0 + 1];
    int cxb2 = cxbase[L0 + 2], cyb2 = cybase[L0 + 2];
    int cxb3 = cxbase[L0 + 3], cyb3 = cybase[L0 + 3];
    constexpr int q = L0 / 4;
    #pragma unroll 1
    for (int it = 0; it < 10; ++it) {
        int pl = it * 64 + lane;
        int rr = pl / 34, cc = pl - rr * 34;
        int gy = ty0 + rr - 1, gx = tx0 + cc - 1;
        uint4 v = make_uint4(0u, 0u, 0u, 0u);
        if ((pl < 612) && ((unsigned)gy < 256u) && ((unsigned)gx < 256u)) {
            v.x = feat1<L0 + 0>(gx, gy, cftab, ctile, cxb0, cyb0);
            v.y = feat1<L0 + 1>(gx, gy, cftab, ctile, cxb1, cyb1);
            v.z = feat1<L0 + 2>(gx, gy, cftab, ctile, cxb2, cyb2);
            v.w = feat1<L0 + 3>(gx, gy, cftab, ctile, cxb3, cyb3);
        }
        if (pl < 612)
            *(uint4*)(xt + (size_t)(pl * 4 + (q ^ (cc & 3))) * 4) = v;
    }
}

// ---- K2: FUSED hash-retrieve + modulation + MFMA 3x3 conv + demod/bias/lrelu ----
// block = one 16x32 output tile of one batch; b = bid&7 (XCD pinning).
__global__ __launch_bounds__(256) void k_conv(
    const float* __restrict__ tables, const float2* __restrict__ cftab,
    const int* __restrict__ ctab, const float* __restrict__ styles,
    const float* __restrict__ cw, const float* __restrict__ cb,
    const float* __restrict__ dcoef, uint32_t* __restrict__ tokens,
    LevelParams p) {
    __shared__ uint32_t xt[18 * 34 * 16];      // 39168 B feature tile (bf16x2 chunks)
    __shared__ uint32_t ctile[2928];           // 11712 B deduped premod corners (bf16x2)
    __shared__ int cxbase[NL], cybase[NL], ncxA[NL], ncyA[NL];

    int bid = blockIdx.x;
    int b = bid & 7;
    int t = bid >> 3;
    int tx0 = (t & 7) * 32, ty0 = (t >> 3) * 16;
    int tid = threadIdx.x;
    int lane = tid & 63, wv = tid >> 6;
    int npx = lane & 15, kg = lane >> 4;
    const float* tb = tables + (size_t)b * NL * TD * 2;

    // A fragments (weights)
    bf16x8 wf[9][2];
    {
        union { bf16x8 v; unsigned short e[8]; } u;
        #pragma unroll
        for (int tp = 0; tp < 9; ++tp)
            #pragma unroll
            for (int ob = 0; ob < 2; ++ob) {
                int o = ob * 16 + npx;
                #pragma unroll
                for (int j = 0; j < 8; ++j)
                    u.e[j] = f2bf(cw[(o * 32 + kg * 8 + j) * 9 + tp]);
                wf[tp][ob] = u.v;
            }
    }
    float dc[2][4], bs[2][4];
    #pragma unroll
    for (int ob = 0; ob < 2; ++ob)
        #pragma unroll
        for (int rg = 0; rg < 4; ++rg) {
            int oc = ob * 16 + kg * 4 + rg;
            dc[ob][rg] = dcoef[b * CH + oc];
            bs[ob][rg] = cb[oc];
        }

    // ---- phase 0a: per-level corner-tile extents ----
    if (tid < NL) {
        int l = tid;
        int cxb = ctab[l * 256 + max(tx0 - 1, 0)];
        int cyb = ctab[l * 256 + max(ty0 - 1, 0)];
        cxbase[l] = cxb;
        cybase[l] = cyb;
        ncxA[l] = ctab[l * 256 + min(tx0 + 32, 255)] - cxb + 2;
        ncyA[l] = ctab[l * 256 + min(ty0 + 16, 255)] - cyb + 2;
    }
    __syncthreads();

    // ---- phase 0b: gather deduped corners, premultiply style, pack bf16x2 ----
    #pragma unroll
    for (int l = 0; l < NL; ++l) {
        const int NCXl = cNCX[l];
        const int CAP = cNCX[l] * cNCY[l];
        float s0 = styles[b * CH + 2 * l], s1 = styles[b * CH + 2 * l + 1];
        for (int u2 = tid; u2 < CAP; u2 += 256) {
            int sy = u2 / NCXl;
            int sx = u2 - sy * NCXl;
            if (sx < ncxA[l] && sy < ncyA[l]) {
                int ax = cxbase[l] + sx, ay = cybase[l] + sy;
                int r = p.res[l];
                uint32_t idx = p.hashed[l]
                    ? (((uint32_t)ax ^ ((uint32_t)ay * PRIME)) & (TD - 1))
                    : (uint32_t)(ay * r + ax);
                float2 g = *(const float2*)(tb + (size_t)l * TD * 2 + 2 * idx);
                ctile[CTOFF[l] + sy * NCXl + sx] = packbf(g.x * s0, g.y * s1);
            }
        }
    }
    __syncthreads();

    // ---- phase 1: wave-uniform level-group feature computation -> xt ----
    switch (wv) {
        case 0: phase1<0>(lane, tx0, ty0, cftab, ctile, cxbase, cybase, xt); break;
        case 1: phase1<4>(lane, tx0, ty0, cftab, ctile, cxbase, cybase, xt); break;
        case 2: phase1<8>(lane, tx0, ty0, cftab, ctile, cxbase, cybase, xt); break;
        default: phase1<12>(lane, tx0, ty0, cftab, ctile, cxbase, cybase, xt); break;
    }
    __syncthreads();

    // ---- phase 2: MFMA conv ----
    #pragma unroll 1
    for (int it = 0; it < 8; ++it) {
        int grp = it * 4 + wv;
        int py_l = grp >> 1;
        int px_l = ((grp & 1) << 4) + npx;
        f32x4 a0 = {0.f, 0.f, 0.f, 0.f};
        f32x4 a1 = {0.f, 0.f, 0.f, 0.f};
        #pragma unroll
        for (int ky = 0; ky < 3; ++ky) {
            int rowb = (py_l + ky) * 34;
            #pragma unroll
            for (int kx = 0; kx < 3; ++kx) {
                int cc = px_l + kx;
                bf16x8 bf = *(const bf16x8*)(xt + (((rowb + cc) << 2) + (kg ^ (cc & 3))) * 4);
                a0 = __builtin_amdgcn_mfma_f32_16x16x32_bf16(wf[ky * 3 + kx][0], bf, a0, 0, 0, 0);
                a1 = __builtin_amdgcn_mfma_f32_16x16x32_bf16(wf[ky * 3 + kx][1], bf, a1, 0, 0, 0);
            }
        }
        int py = ty0 + py_l, px = tx0 + px_l;
        size_t pbase = (size_t)py * 256 + px;
        {
            float y0 = a0[0] * dc[0][0] + bs[0][0];
            float y1 = a0[1] * dc[0][1] + bs[0][1];
            float y2 = a0[2] * dc[0][2] + bs[0][2];
            float y3 = a0[3] * dc[0][3] + bs[0][3];
            y0 = (y0 > 0.f ? y0 : 0.2f * y0) * 1.4142135623730951f;
            y1 = (y1 > 0.f ? y1 : 0.2f * y1) * 1.4142135623730951f;
            y2 = (y2 > 0.f ? y2 : 0.2f * y2) * 1.4142135623730951f;
            y3 = (y3 > 0.f ? y3 : 0.2f * y3) * 1.4142135623730951f;
            int lp0 = kg * 2;
            tokens[((size_t)(b * NL + lp0)) * NPIX + pbase] = packbf(y0, y1);
            tokens[((size_t)(b * NL + lp0 + 1)) * NPIX + pbase] = packbf(y2, y3);
        }
        {
            float y0 = a1[0] * dc[1][0] + bs[1][0];
            float y1 = a1[1] * dc[1][1] + bs[1][1];
            float y2 = a1[2] * dc[1][2] + bs[1][2];
            float y3 = a1[3] * dc[1][3] + bs[1][3];
            y0 = (y0 > 0.f ? y0 : 0.2f * y0) * 1.4142135623730951f;
            y1 = (y1 > 0.f ? y1 : 0.2f * y1) * 1.4142135623730951f;
            y2 = (y2 > 0.f ? y2 : 0.2f * y2) * 1.4142135623730951f;
            y3 = (y3 > 0.f ? y3 : 0.2f * y3) * 1.4142135623730951f;
            int lp0 = 8 + kg * 2;
            tokens[((size_t)(b * NL + lp0)) * NPIX + pbase] = packbf(y0, y1);
            tokens[((size_t)(b * NL + lp0 + 1)) * NPIX + pbase] = packbf(y2, y3);
        }
    }
}

// ---- K3a: recon stage 1, direct form — wave per (l, row i, 64-wide cx chunk) ----
__global__ __launch_bounds__(256) void k_recon1(const uint32_t* __restrict__ tokens,
                                                const int* __restrict__ ctab,
                                                const float* __restrict__ ftab,
                                                const int* __restrict__ stab,
                                                float* __restrict__ U, LevelParams p) {
    int wid = blockIdx.x * 4 + (threadIdx.x >> 6);
    int lane = threadIdx.x & 63;
    int b = blockIdx.y;
    if (wid >= p.n1waves) return;
    int l = 0;
    #pragma unroll
    for (int q = 1; q < NL; ++q) if (wid >= p.r1off[q]) l = q;
    int u = wid - p.r1off[l];
    int nck = p.nck[l];
    int i = u / nck;
    int ck = u - i * nck;
    int r = p.res[l];
    int cx = ck * 64 + lane;
    bool valid = cx < r;
    const int* Sl = stab + p.soff[l];
    int jlo = 1, jhi = 0;
    if (valid) {
        jlo = (cx > 0) ? Sl[cx - 1] : 0;
        jhi = Sl[min(cx + 1, r)] - 1;
    }
    const uint32_t* trow = tokens + (size_t)(b * NL + l) * NPIX + i * 256;
    const int* crow = ctab + l * 256;
    const float* frow = ftab + l * 256;
    float a0 = 0.f, a1 = 0.f;
    for (int j = jlo; j <= jhi; ++j) {
        int c = crow[j];
        float f = frow[j];
        float w = (c == cx) ? (1.f - f) : f;
        uint32_t tv = trow[j];
        a0 += w * bflo(tv);
        a1 += w * bfhi(tv);
    }
    if (valid)
        *(float2*)(U + (size_t)b * (p.sumr * 512) + p.uoff[l] + ((size_t)i * r + cx) * 2)
            = make_float2(a0, a1);
}

// ---- K3b: recon stage 2 — wave per (level, cy, 64-wide cx chunk) ----
__global__ __launch_bounds__(256) void k_recon2(const float* __restrict__ U,
                                                const int* __restrict__ ctab,
                                                const float* __restrict__ ftab,
                                                const int* __restrict__ stab,
                                                float* __restrict__ R, LevelParams p) {
    int wid = blockIdx.x * 4 + (threadIdx.x >> 6);
    int lane = threadIdx.x & 63;
    int b = blockIdx.y;
    if (wid >= p.nwaves) return;
    int l = 0;
    #pragma unroll
    for (int q = 1; q < NL; ++q) if (wid >= p.cwoff[q]) l = q;
    int u = wid - p.cwoff[l];
    int r = p.res[l];
    int nck = p.nck[l];
    int cy = u / nck;
    int ck = u - cy * nck;
    int cx = ck * 64 + lane;
    bool valid = cx < r;
    const int* Sl = stab + p.soff[l];
    int ilo = (cy > 0) ? Sl[cy - 1] : 0;
    int ihi = Sl[min(cy + 1, r)] - 1;
    const float* Ub = U + (size_t)b * (p.sumr * 512) + p.uoff[l];
    const int* crow = ctab + l * 256;
    const float* frow = ftab + l * 256;
    float a0 = 0.f, a1 = 0.f;
    for (int i = ilo; i <= ihi; ++i) {
        int c = crow[i];
        float f = frow[i];
        float w = (c == cy) ? (1.f - f) : f;
        if (valid) {
            float2 uu = *(const float2*)(Ub + ((size_t)i * r + cx) * 2);
            a0 += w * uu.x;
            a1 += w * uu.y;
        }
    }
    if (!valid) return;
    float* Rbl = R + (size_t)(b * NL + l) * TD * 2;
    if (p.hashed[l]) {
        uint32_t h = ((uint32_t)cx ^ ((uint32_t)cy * PRIME)) & (TD - 1);
        atomicAdd(&Rbl[2 * h], a0);
        atomicAdd(&Rbl[2 * h + 1], a1);
    } else {
        *(float2*)(Rbl + 2 * (cy * r + cx)) = make_float2(a0, a1);
    }
}

// ---- K4: residual + LayerNorm(16384) -> FP32 out ----
__global__ __launch_bounds__(512) void k_ln(const float* __restrict__ R,
                                            const float* __restrict__ inp,
                                            float* __restrict__ out) {
    int row = blockIdx.x;                       // b*NL + l
    const float4* rv = (const float4*)(R + (size_t)row * 16384);
    const float4* iv = (const float4*)(inp + (size_t)row * 16384);
    int tid = threadIdx.x;
    float sum = 0.f, ssq = 0.f;
    for (int k = tid; k < 4096; k += 512) {
        float4 a = rv[k], c = iv[k];
        float x0 = a.x + c.x, x1 = a.y + c.y, x2 = a.z + c.z, x3 = a.w + c.w;
        sum += x0 + x1 + x2 + x3;
        ssq += x0 * x0 + x1 * x1 + x2 * x2 + x3 * x3;
    }
    #pragma unroll
    for (int off = 32; off > 0; off >>= 1) {
        sum += __shfl_xor(sum, off, 64);
        ssq += __shfl_xor(ssq, off, 64);
    }
    __shared__ float red[16];
    int w = tid >> 6;
    if ((tid & 63) == 0) { red[w * 2] = sum; red[w * 2 + 1] = ssq; }
    __syncthreads();
    sum = 0.f; ssq = 0.f;
    #pragma unroll
    for (int q = 0; q < 8; ++q) { sum += red[q * 2]; ssq += red[q * 2 + 1]; }
    float mu = sum * (1.f / 16384.f);
    float var = ssq * (1.f / 16384.f) - mu * mu;
    float inv = rsqrtf(var + 1e-5f);
    float4* ob = (float4*)(out + (size_t)row * 16384);
    for (int k = tid; k < 4096; k += 512) {
        float4 a = rv[k], c = iv[k];
        float4 o4;
        o4.x = (a.x + c.x - mu) * inv;
        o4.y = (a.y + c.y - mu) * inv;
        o4.z = (a.z + c.z - mu) * inv;
        o4.w = (a.w + c.w - mu) * inv;
        ob[k] = o4;
    }
}

extern "C" void kernel_launch(void* const* d_in, const int* in_sizes, int n_in,
                              void* d_out, int out_size, void* d_ws, size_t ws_size,
                              hipStream_t stream) {
    const float* inputs = (const float*)d_in[0];
    const float* s      = (const float*)d_in[1];
    const float* coords = (const float*)d_in[2];
    const float* aw     = (const float*)d_in[3];
    const float* ab     = (const float*)d_in[4];
    const float* cw     = (const float*)d_in[5];
    const float* cb     = (const float*)d_in[6];

    char* ws = (char*)d_ws;
    float*    U      = (float*)(ws);                    // 23.4 MB used
    uint32_t* tokens = (uint32_t*)(ws + 33554432);      // 33,554,432 B
    float*    R      = (float*)(ws + 67108864);         //  8,388,608 B
    float*    styles = (float*)(ws + 75497472);
    float*    dcoef  = (float*)(ws + 75498496);
    int*      ctab   = (int*)(ws + 75499520);           // 16 KB
    float*    ftab   = (float*)(ws + 75515904);         // 16 KB
    int*      stab   = (int*)(ws + 75532288);           // ~6 KB
    float2*   cftab  = (float2*)(ws + 75540480);        // 32 KB

    // RES_LIST exactly as numpy computes it (double libm ops).
    LevelParams p;
    double bb = exp((log(256.0) - log(16.0)) / 15.0);
    int uoff = 0, soff = 0, cwoff = 0, r1off = 0;
    for (int l = 0; l < NL; ++l) {
        int r = (int)floor(16.0 * pow(bb, (double)l));
        p.res[l] = r;
        p.hashed[l] = (r * r > TD) ? 1 : 0;
        p.uoff[l] = uoff;
        p.soff[l] = soff;
        p.cwoff[l] = cwoff;
        p.r1off[l] = r1off;
        int nck = (r + 63) >> 6;
        p.nck[l] = nck;
        uoff += r * 512;
        soff += r + 2;
        cwoff += r * nck;
        r1off += 256 * nck;
    }
    p.sumr = uoff / 512;
    p.nwaves = cwoff;
    p.n1waves = r1off;

    hipMemsetAsync(R, 0, (size_t)NB * NL * TD * 2 * sizeof(float), stream);
    hipLaunchKernelGGL(k_styles, dim3(NB), dim3(256), 0, stream, s, aw, ab, cw, styles, dcoef);
    hipLaunchKernelGGL(k_wtab, dim3(NL), dim3(256), 0, stream, coords, ctab, ftab, cftab, stab, p);
    hipLaunchKernelGGL(k_conv, dim3(1024), dim3(256), 0, stream,
                       inputs, cftab, ctab, styles, cw, cb, dcoef, tokens, p);
    hipLaunchKernelGGL(k_recon1, dim3((p.n1waves + 3) / 4, NB), dim3(256), 0, stream,
                       tokens, ctab, ftab, stab, U, p);
    hipLaunchKernelGGL(k_recon2, dim3((p.nwaves + 3) / 4, NB), dim3(256), 0, stream,
                       U, ctab, ftab, stab, R, p);
    hipLaunchKernelGGL(k_ln, dim3(NB * NL), dim3(512), 0, stream,
                       R, inputs, (float*)d_out);
}